// Round 7
// baseline (254.417 us; speedup 1.0000x reference)
//
#include <hip/hip_runtime.h>
#include <hip/hip_bf16.h>

#define B_ 4
#define S_ 1024
#define E_ 1280
#define H_ 16
#define D_ 80
#define M_ (B_*S_)   // 4096

typedef __hip_bfloat16 bf16;
using bf16x8 = __attribute__((ext_vector_type(8))) short;  // 8 bf16 = 4 VGPRs
using f32x4  = __attribute__((ext_vector_type(4))) float;  // MFMA C/D frag

__device__ __forceinline__ float b2f(bf16 x){ return __bfloat162float(x); }
__device__ __forceinline__ bf16  f2b(float x){ return __float2bfloat16(x); }

__device__ __forceinline__ void gload_lds16(const void* g, void* l) {
    __builtin_amdgcn_global_load_lds(
        (const __attribute__((address_space(1))) unsigned int*)g,
        (__attribute__((address_space(3))) unsigned int*)l, 16, 0, 0);
}

// 8-phase sync helpers (rule #18: sched_barrier(0) after inline waitcnt)
__device__ __forceinline__ void ph_begin() {
    __builtin_amdgcn_s_barrier();
    asm volatile("s_waitcnt lgkmcnt(0)" ::: "memory");
    __builtin_amdgcn_sched_barrier(0);
    __builtin_amdgcn_s_setprio(1);
}
__device__ __forceinline__ void ph_end() {
    __builtin_amdgcn_s_setprio(0);
    __builtin_amdgcn_sched_barrier(0);
    __builtin_amdgcn_s_barrier();
}
__device__ __forceinline__ void ph_end_vm6() {
    __builtin_amdgcn_s_setprio(0);
    __builtin_amdgcn_sched_barrier(0);
    asm volatile("s_waitcnt vmcnt(6)" ::: "memory");
    __builtin_amdgcn_s_barrier();
}
__device__ __forceinline__ void ph_end_vm0() {
    __builtin_amdgcn_s_setprio(0);
    __builtin_amdgcn_sched_barrier(0);
    asm volatile("s_waitcnt vmcnt(0)" ::: "memory");
    __builtin_amdgcn_s_barrier();
}

// fp32 -> bf16 conversion, 8 elems/thread. blockIdx.y selects segment.
__global__ __launch_bounds__(256) void cvt_kernel(
    const float* __restrict__ s0, const float* __restrict__ s1,
    const float* __restrict__ s2, const float* __restrict__ s3,
    const float* __restrict__ s4,
    bf16* __restrict__ d0, bf16* __restrict__ d1, bf16* __restrict__ d2,
    bf16* __restrict__ d3, bf16* __restrict__ d4,
    int n0, int n1)
{
    const float* s; bf16* d; int n;
    switch (blockIdx.y) {
        case 0: s = s0; d = d0; n = n0; break;
        case 1: s = s1; d = d1; n = n1; break;
        case 2: s = s2; d = d2; n = n1; break;
        case 3: s = s3; d = d3; n = n1; break;
        default: s = s4; d = d4; n = n1; break;
    }
    int i = (blockIdx.x * 256 + threadIdx.x) * 8;
    if (i >= n) return;
    float4 a = *(const float4*)(s + i);
    float4 b = *(const float4*)(s + i + 4);
    bf16 t[8];
    t[0]=f2b(a.x); t[1]=f2b(a.y); t[2]=f2b(a.z); t[3]=f2b(a.w);
    t[4]=f2b(b.x); t[5]=f2b(b.y); t[6]=f2b(b.z); t[7]=f2b(b.w);
    *(uint4*)(d + i) = *(const uint4*)t;
}

// ============================================================================
// QKV projection: 256x256 8-phase MFMA GEMM (T2+T3+T4+T5). Identity block
// mapping (r6 XCD remap REVERTED: it made each XCD read ALL of A (10.5 MB)
// instead of 2 strips — FETCH 43.7->48.1 MB, dur 54->63 µs).
// ============================================================================
__global__ __launch_bounds__(512, 2) void qkv_gemm_8ph(
    const bf16* __restrict__ A,
    const bf16* __restrict__ W0, const bf16* __restrict__ W1, const bf16* __restrict__ W2,
    const float* __restrict__ b0, const float* __restrict__ b1, const float* __restrict__ b2,
    bf16* __restrict__ Cq, bf16* __restrict__ Ck, bf16* __restrict__ Cv)
{
    constexpr int K = 1280;
    constexpr int NITER = K / 128;   // 10 iterations, 2 K-tiles each

    __shared__ __align__(16) bf16 Asm[2][2][128*64];   // [buf][half][row*64+col]
    __shared__ __align__(16) bf16 Bsm[2][2][128*64];

    const int bm  = blockIdx.x * 256;
    const int ny  = blockIdx.y;            // 0..14
    const int mat = ny / 5;
    const int bn  = (ny % 5) * 256;        // col base within matrix
    const bf16*  W    = (mat == 0) ? W0 : (mat == 1) ? W1 : W2;
    const float* bias = (mat == 0) ? b0 : (mat == 1) ? b1 : b2;

    const int tid  = threadIdx.x;
    const int lane = tid & 63, wv = tid >> 6;
    const int wm = wv >> 2, wn = wv & 3;        // wave tile: rows wm*128, cols wn*64
    const int quad = lane >> 4, l15 = lane & 15;

    auto stageA = [&](int j_, int half) {
        #pragma unroll
        for (int i = 0; i < 2; i++) {
            const int c   = tid + i*512;
            const int row = c >> 3;
            const int g   = (c & 7) ^ (row & 7);
            gload_lds16(A + (size_t)(bm + half*128 + row) * K + j_*64 + g*8,
                        &Asm[j_ & 1][half][(wv*64 + i*512) * 8]);
        }
    };
    auto stageB = [&](int j_, int half) {
        #pragma unroll
        for (int i = 0; i < 2; i++) {
            const int c   = tid + i*512;
            const int row = c >> 3;
            const int g   = (c & 7) ^ (row & 7);
            gload_lds16(W + (size_t)(bn + half*128 + row) * K + j_*64 + g*8,
                        &Bsm[j_ & 1][half][(wv*64 + i*512) * 8]);
        }
    };
    auto lda = [&](int bf, int mt, int ks) -> bf16x8 {
        const int r = mt*16 + l15;
        return *(const bf16x8*)&Asm[bf][wm][r*64 + (((quad + ks*4) ^ (r & 7)) << 3)];
    };
    auto ldb = [&](int bf, int nt, int ks) -> bf16x8 {
        const int r = (wn & 1)*64 + nt*16 + l15;
        return *(const bf16x8*)&Bsm[bf][wn >> 1][r*64 + (((quad + ks*4) ^ (r & 7)) << 3)];
    };

    f32x4 acc[8][4] = {};
    bf16x8 a[4][2], bA[2][2], bB[2][2];

#define MFMA_Q(MT0, NT0, BB_) do { \
    _Pragma("unroll") for (int mt_ = 0; mt_ < 4; mt_++) \
    _Pragma("unroll") for (int nt_ = 0; nt_ < 2; nt_++) \
    _Pragma("unroll") for (int ks_ = 0; ks_ < 2; ks_++) \
        acc[(MT0)+mt_][(NT0)+nt_] = __builtin_amdgcn_mfma_f32_16x16x32_bf16( \
            a[mt_][ks_], BB_[nt_][ks_], acc[(MT0)+mt_][(NT0)+nt_], 0, 0, 0); \
} while (0)

    stageA(0, 0); stageA(0, 1); stageB(0, 0); stageB(0, 1);
    stageA(1, 0); stageA(1, 1); stageB(1, 0); stageB(1, 1);
    __syncthreads();

    for (int t = 0; t < NITER; t++) {
        const int  j  = 2*t;
        const bool pf = (t + 1 < NITER);

        #pragma unroll
        for (int mt = 0; mt < 4; mt++) { a[mt][0] = lda(0, mt, 0); a[mt][1] = lda(0, mt, 1); }
        #pragma unroll
        for (int nt = 0; nt < 2; nt++) { bA[nt][0] = ldb(0, nt, 0); bA[nt][1] = ldb(0, nt, 1); }
        stageA(j+1, 1);
        ph_begin(); MFMA_Q(0, 0, bA); ph_end();

        #pragma unroll
        for (int nt = 0; nt < 2; nt++) { bB[nt][0] = ldb(0, 2+nt, 0); bB[nt][1] = ldb(0, 2+nt, 1); }
        ph_begin(); MFMA_Q(0, 2, bB); ph_end();

        #pragma unroll
        for (int mt = 0; mt < 4; mt++) { a[mt][0] = lda(0, 4+mt, 0); a[mt][1] = lda(0, 4+mt, 1); }
        if (pf) stageB(j+2, 0);
        ph_begin(); MFMA_Q(4, 0, bA); ph_end();

        if (pf) { stageB(j+2, 1); stageA(j+2, 0); }
        ph_begin(); MFMA_Q(4, 2, bB);
        if (pf) ph_end_vm6(); else ph_end_vm0();

        #pragma unroll
        for (int mt = 0; mt < 4; mt++) { a[mt][0] = lda(1, mt, 0); a[mt][1] = lda(1, mt, 1); }
        #pragma unroll
        for (int nt = 0; nt < 2; nt++) { bA[nt][0] = ldb(1, nt, 0); bA[nt][1] = ldb(1, nt, 1); }
        if (pf) stageA(j+2, 1);
        ph_begin(); MFMA_Q(0, 0, bA); ph_end();

        #pragma unroll
        for (int nt = 0; nt < 2; nt++) { bB[nt][0] = ldb(1, 2+nt, 0); bB[nt][1] = ldb(1, 2+nt, 1); }
        ph_begin(); MFMA_Q(0, 2, bB); ph_end();

        #pragma unroll
        for (int mt = 0; mt < 4; mt++) { a[mt][0] = lda(1, 4+mt, 0); a[mt][1] = lda(1, 4+mt, 1); }
        if (pf) stageB(j+3, 0);
        ph_begin(); MFMA_Q(4, 0, bA); ph_end();

        if (pf) { stageB(j+3, 1); stageA(j+3, 0); }
        ph_begin(); MFMA_Q(4, 2, bB); ph_end_vm6();
    }
#undef MFMA_Q

    if (mat < 2) {
        bf16* C = (mat == 0) ? Cq : Ck;
        #pragma unroll
        for (int nt = 0; nt < 4; nt++) {
            const int ncol = bn + wn*64 + nt*16 + l15;
            const float bv = bias[ncol];
            #pragma unroll
            for (int mt = 0; mt < 8; mt++) {
                const int m0 = bm + wm*128 + mt*16 + quad*4;
                #pragma unroll
                for (int r = 0; r < 4; r++)
                    C[(size_t)(m0 + r) * E_ + ncol] = f2b(acc[mt][nt][r] + bv);
            }
        }
    } else {
        #pragma unroll
        for (int nt = 0; nt < 4; nt++) {
            const int ncol = bn + wn*64 + nt*16 + l15;
            const float bv = bias[ncol];
            const int hh = ncol / 80, dd = ncol % 80;
            #pragma unroll
            for (int mt = 0; mt < 8; mt++) {
                const int m0  = bm + wm*128 + mt*16 + quad*4;
                const int btok = m0 >> 10;
                const int key  = m0 & 1023;
                union { bf16 h[4]; uint2 u; } t4;
                #pragma unroll
                for (int r = 0; r < 4; r++) t4.h[r] = f2b(acc[mt][nt][r] + bv);
                *(uint2*)&Cv[((size_t)(btok*H_ + hh)*D_ + dd)*S_ + key] = t4.u;
            }
        }
    }
}

// ============================================================================
// Output projection: 128x128 m97-style GEMM, SWAPPED MFMA operands:
// acc = mfma(wf, af) -> lane owns output row m = l15 and 4 consecutive cols
// n = nt*16 + quad*4 + r  =>  epilogue is 16 float4 stores instead of 128
// scalar dword stores. Fragment layouts of A/B operands are identical, so
// the LDS reads are unchanged (same trick verified in attention v11).
// ============================================================================
__global__ __launch_bounds__(256) void oproj_gemm(
    const bf16* __restrict__ A, const bf16* __restrict__ W,
    const float* __restrict__ bias, float* __restrict__ C)
{
    const int K = E_, N = E_;
    const int bn = blockIdx.y * 128;
    const int bm = blockIdx.x * 128;

    __shared__ bf16 As[2][128][32];
    __shared__ bf16 Ws[2][128][32];

    const int tid  = threadIdx.x;
    const int lane = tid & 63;
    const int wv   = tid >> 6;
    const int wm   = (wv & 1) * 64;
    const int wn   = (wv >> 1) * 64;
    const int srow = wv * 16 + (lane >> 2);
    const int scol = (lane & 3) * 8;

    f32x4 acc[4][4] = {};

    for (int k0 = 0; k0 < K; k0 += 64) {
        __syncthreads();
        #pragma unroll
        for (int p = 0; p < 2; p++) {
            const int kc = k0 + p*32 + scol;
            gload_lds16(A + (size_t)(bm + srow)      * K + kc, &As[p][wv*16][0]);
            gload_lds16(A + (size_t)(bm + 64 + srow) * K + kc, &As[p][64 + wv*16][0]);
            gload_lds16(W + (size_t)(bn + srow)      * K + kc, &Ws[p][wv*16][0]);
            gload_lds16(W + (size_t)(bn + 64 + srow) * K + kc, &Ws[p][64 + wv*16][0]);
        }
        __syncthreads();

        const int fr = lane & 15;
        const int kq = (lane >> 4) * 8;
        #pragma unroll
        for (int p = 0; p < 2; p++) {
            bf16x8 af[4], wf[4];
            #pragma unroll
            for (int t = 0; t < 4; t++) {
                af[t] = *(const bf16x8*)&As[p][wm + t*16 + fr][kq];
                wf[t] = *(const bf16x8*)&Ws[p][wn + t*16 + fr][kq];
            }
            #pragma unroll
            for (int mt = 0; mt < 4; mt++)
                #pragma unroll
                for (int nt = 0; nt < 4; nt++)
                    acc[mt][nt] = __builtin_amdgcn_mfma_f32_16x16x32_bf16(
                        wf[nt], af[mt], acc[mt][nt], 0, 0, 0);   // SWAPPED
        }
    }

    const int l15  = lane & 15;
    const int quad = lane >> 4;
    #pragma unroll
    for (int nt = 0; nt < 4; nt++) {
        const int n0 = bn + wn + nt*16 + quad*4;
        const float4 bv4 = *(const float4*)&bias[n0];
        #pragma unroll
        for (int mt = 0; mt < 4; mt++) {
            const int m = bm + wm + mt*16 + l15;
            float4 o4;
            o4.x = acc[mt][nt][0] + bv4.x;
            o4.y = acc[mt][nt][1] + bv4.y;
            o4.z = acc[mt][nt][2] + bv4.z;
            o4.w = acc[mt][nt][3] + bv4.w;
            *(float4*)&C[(size_t)m * N + n0] = o4;
        }
    }
}

// rope helper
__device__ __forceinline__ void rope8(const bf16* lo, const bf16* hi,
                                      const float* cp, const float* sp,
                                      float mul, uint4* out_lo, uint4* out_hi)
{
    union { uint4 u; bf16 h[8]; } li, hi_, lo_o, hi_o;
    li.u  = *(const uint4*)lo;
    hi_.u = *(const uint4*)hi;
    #pragma unroll
    for (int u = 0; u < 8; u++) {
        float x1 = b2f(li.h[u]), x2 = b2f(hi_.h[u]);
        float c = cp[u], s = sp[u];
        lo_o.h[u] = f2b((x1*c - x2*s) * mul);
        hi_o.h[u] = f2b((x2*c + x1*s) * mul);
    }
    *out_lo = lo_o.u;
    *out_hi = hi_o.u;
}

// One-shot in-place RoPE over q and k. Q additionally pre-scaled by 1/sqrt(80).
__global__ __launch_bounds__(256) void rope_kernel(
    bf16* __restrict__ qp, bf16* __restrict__ kp,
    const float* __restrict__ cosp, const float* __restrict__ sinp)
{
    int idx = blockIdx.x * 256 + threadIdx.x;
    const int NT = M_ * H_ * 5;   // 327680
    bf16* base; float mul;
    if (idx < NT) { base = qp; mul = 0.11180339887498949f; }
    else         { base = kp; mul = 1.0f; idx -= NT; }
    const int row = idx / 80;
    const int rem = idx - row * 80;
    const int h   = rem / 5;
    const int pc  = rem - h * 5;
    const int s   = row & (S_ - 1);
    bf16* p = base + (size_t)row * E_ + h * D_ + pc * 8;
    const float* cp = cosp + s * D_ + pc * 8;
    const float* sp = sinp + s * D_ + pc * 8;
    uint4 olo, ohi;
    rope8(p, p + 40, cp, sp, mul, &olo, &ohi);
    *(uint4*)p        = olo;
    *(uint4*)(p + 40) = ohi;
}

// ============================================================================
// MFMA flash attention v12b — 32 q-rows/wave + RESTORED __launch_bounds__
// (512,4): r6's v12 dropped the min-waves arg -> compiler free to exceed 128
// VGPR -> 1 block/CU -> DS-amortization masked by halved occupancy. (512,4)
// caps VGPR at 128 -> 2 blocks/CU (LDS 73.7 KB x2 = 147 KB < 160 KB).
// Spill tell: attn WRITE_SIZE > 10 MB.
// ============================================================================
__global__ __launch_bounds__(512, 4) void attn_mfma(
    const bf16* __restrict__ q, const bf16* __restrict__ k, const bf16* __restrict__ vt,
    const int* __restrict__ cu, bf16* __restrict__ o)
{
    __shared__ __align__(16) bf16 Ks[2][64*80];      // swizzled
    __shared__ __align__(16) bf16 VTs[2][80*64];     // swizzled
    __shared__ __align__(16) bf16 PTq[8][2][16*64];  // per-wave, per-group P

    const int n  = blockIdx.x;                 // 256 blocks
    const int g  = ((n >> 5) << 3) | (n & 7);  // (b,h): XCD = n&7 = h&7
    const int qs = (n >> 3) & 3;               // q-supertile 0..3 (256 rows)
    const int b  = g >> 4;
    const int h  = g & 15;

    const int tid  = threadIdx.x;
    const int lane = tid & 63, wv = tid >> 6;  // wv 0..7
    const int quad = lane >> 4, l15 = lane & 15;
    const int q0   = qs * 256;
    const int len  = cu[b + 1] - cu[b];

    const bool uniformq = (q0 >= len);
    const bool fast     = !uniformq && ((q0 + 256) <= len) && ((len & 63) == 0);
    const int  ktiles   = uniformq ? 16 : (fast ? (len >> 6) : 16);
    const bool domask   = !uniformq && !fast;

    bf16* PTa = &PTq[wv][0][0];
    bf16* PTb = &PTq[wv][1][0];

    // Q fragments (B-operand): two query groups, rows wv*32+l15 and +16.
    bf16x8 qfA[3] = {}, qfB[3] = {};
    if (!uniformq) {
        const bf16* qra = q + (size_t)(b*S_ + q0 + wv*32 + l15)*E_ + h*D_ + quad*8;
        qfA[0] = *(const bf16x8*)(qra);
        qfA[1] = *(const bf16x8*)(qra + 32);
        if (quad < 2) qfA[2] = *(const bf16x8*)(qra + 64);
        const bf16* qrb = qra + (size_t)16 * E_;
        qfB[0] = *(const bf16x8*)(qrb);
        qfB[1] = *(const bf16x8*)(qrb + 32);
        if (quad < 2) qfB[2] = *(const bf16x8*)(qrb + 64);
    }

    float mA = -1e30f, lA = 0.f, mB = -1e30f, lB = 0.f;
    f32x4 oA[5] = {}, oB[5] = {};

    bf16x8 pone;
    {
        const short one_s = (short)0x3F80;   // bf16 1.0
        #pragma unroll
        for (int i = 0; i < 8; i++) pone[i] = one_s;
    }

    const int u_  = l15 >> 2;
    const int s0r = quad ^ u_;            // K granule ks=0
    const int sv0 = quad ^ (l15 & 7);     // V granule ks=0

    auto stage = [&](int kt, int bf) {
        #pragma unroll
        for (int i = 0; i < 3; i++) {
            int c = tid + i * 512;
            if (c < 640) {
                if (!uniformq) {
                    int row = c / 10, s5 = c - row * 10;
                    int uu = (row >> 2) & 3;
                    int sg = (s5 < 8) ? (s5 ^ uu) : (8 + ((s5 ^ uu) & 1));
                    gload_lds16(k + (size_t)(b*S_ + kt*64 + row)*E_ + h*D_ + sg*8,
                                &Ks[bf][c*8]);
                }
            } else if (c < 1280) {
                int c2 = c - 640;
                int row = c2 >> 3, s5 = c2 & 7;
                int sg = s5 ^ (row & 7);
                gload_lds16(vt + ((size_t)(b*H_ + h)*D_ + row)*S_ + kt*64 + sg*8,
                            &VTs[bf][c2*8]);
            }
        }
    };

    stage(0, 0);
    __syncthreads();   // buf0 ready

    // per-group online softmax + P-write
    auto softmax_pt = [&](f32x4* s4, float& m_s, float& l_s, f32x4* oc,
                          bf16* PTg, bool vq, int kt) {
        float sv[4][4];
        if (!domask) {
            #pragma unroll
            for (int nt = 0; nt < 4; nt++)
                #pragma unroll
                for (int r = 0; r < 4; r++)
                    sv[nt][r] = s4[nt][r];
        } else {
            #pragma unroll
            for (int nt = 0; nt < 4; nt++)
                #pragma unroll
                for (int r = 0; r < 4; r++) {
                    const bool vk = (kt*64 + nt*16 + quad*4 + r) < len;
                    sv[nt][r] = (vq && vk) ? s4[nt][r] : -1e9f;
                }
        }
        float rm[4];
        #pragma unroll
        for (int nt = 0; nt < 4; nt++)
            rm[nt] = fmaxf(fmaxf(sv[nt][0], sv[nt][1]), fmaxf(sv[nt][2], sv[nt][3]));
        float sloc = fmaxf(fmaxf(rm[0], rm[1]), fmaxf(rm[2], rm[3]));
        sloc = fmaxf(sloc, __shfl_xor(sloc, 16, 64));
        sloc = fmaxf(sloc, __shfl_xor(sloc, 32, 64));
        const float mnew  = fmaxf(m_s, sloc);
        const float alpha = __expf(m_s - mnew);
        float p[4][4], lsum = 0.f;
        #pragma unroll
        for (int nt = 0; nt < 4; nt++)
            #pragma unroll
            for (int r = 0; r < 4; r++) {
                p[nt][r] = __expf(sv[nt][r] - mnew);
                lsum += p[nt][r];
            }
        lsum += __shfl_xor(lsum, 16, 64);
        lsum += __shfl_xor(lsum, 32, 64);
        l_s = l_s * alpha + lsum;
        m_s = mnew;
        #pragma unroll
        for (int dt = 0; dt < 5; dt++)
            #pragma unroll
            for (int r = 0; r < 4; r++)
                oc[dt][r] *= alpha;
        #pragma unroll
        for (int nt = 0; nt < 4; nt++) {
            union { bf16 hh[4]; uint2 u; } w;
            #pragma unroll
            for (int r = 0; r < 4; r++) w.hh[r] = f2b(p[nt][r]);
            const int gw = (2*nt + (quad >> 1)) ^ (l15 & 7);
            *(uint2*)&PTg[l15*64 + gw*8 + (quad & 1)*4] = w.u;
        }
    };

    for (int kt = 0; kt < ktiles; kt++) {
        const int cur = kt & 1;
        if (kt + 1 < ktiles) stage(kt + 1, cur ^ 1);   // loads fly during compute

        bf16x8 pfA0 = pone, pfA1 = pone, pfB0 = pone, pfB1 = pone;
        if (!uniformq) {
            // ---- QK^T swapped: A=K, B=Q; K frags shared by both query groups
            f32x4 sa[4], sb[4];
            #pragma unroll
            for (int nt = 0; nt < 4; nt++) {
                const bf16* kr = &Ks[cur][(nt*16 + l15) * 80];
                bf16x8 kf0 = *(const bf16x8*)(kr + s0r*8);
                bf16x8 kf1 = *(const bf16x8*)(kr + 32 + s0r*8);
                bf16x8 kf2 = {};
                if (quad < 2) kf2 = *(const bf16x8*)(kr + 64 + (s0r & 1)*8);
                f32x4 a0 = {}, b0 = {};
                a0 = __builtin_amdgcn_mfma_f32_16x16x32_bf16(kf0, qfA[0], a0, 0, 0, 0);
                a0 = __builtin_amdgcn_mfma_f32_16x16x32_bf16(kf1, qfA[1], a0, 0, 0, 0);
                a0 = __builtin_amdgcn_mfma_f32_16x16x32_bf16(kf2, qfA[2], a0, 0, 0, 0);
                b0 = __builtin_amdgcn_mfma_f32_16x16x32_bf16(kf0, qfB[0], b0, 0, 0, 0);
                b0 = __builtin_amdgcn_mfma_f32_16x16x32_bf16(kf1, qfB[1], b0, 0, 0, 0);
                b0 = __builtin_amdgcn_mfma_f32_16x16x32_bf16(kf2, qfB[2], b0, 0, 0, 0);
                sa[nt] = a0; sb[nt] = b0;
            }

            const bool vqA = (q0 + wv*32 + l15) < len;
            const bool vqB = (q0 + wv*32 + 16 + l15) < len;
            softmax_pt(sa, mA, lA, oA, PTa, vqA, kt);
            softmax_pt(sb, mB, lB, oB, PTb, vqB, kt);

            // P-frags (same-wave RAW via lgkmcnt)
            pfA0 = *(const bf16x8*)&PTa[l15*64 + ((quad    ) ^ (l15 & 7))*8];
            pfA1 = *(const bf16x8*)&PTa[l15*64 + ((quad + 4) ^ (l15 & 7))*8];
            pfB0 = *(const bf16x8*)&PTb[l15*64 + ((quad    ) ^ (l15 & 7))*8];
            pfB1 = *(const bf16x8*)&PTb[l15*64 + ((quad + 4) ^ (l15 & 7))*8];
        }

        // ---- PV: V frags shared by both groups
        #pragma unroll
        for (int dt = 0; dt < 5; dt++) {
            const bf16* vr = &VTs[cur][(dt*16 + l15) * 64];
            bf16x8 vf0 = *(const bf16x8*)(vr + sv0*8);
            bf16x8 vf1 = *(const bf16x8*)(vr + (sv0 ^ 4)*8);
            oA[dt] = __builtin_amdgcn_mfma_f32_16x16x32_bf16(vf0, pfA0, oA[dt], 0, 0, 0);
            oA[dt] = __builtin_amdgcn_mfma_f32_16x16x32_bf16(vf1, pfA1, oA[dt], 0, 0, 0);
            oB[dt] = __builtin_amdgcn_mfma_f32_16x16x32_bf16(vf0, pfB0, oB[dt], 0, 0, 0);
            oB[dt] = __builtin_amdgcn_mfma_f32_16x16x32_bf16(vf1, pfB1, oB[dt], 0, 0, 0);
        }
        __syncthreads();   // reads of buf[cur] done; buf[cur^1] loads drained
    }

    // ---- epilogue: group A row, group B row (+16)
    {
        const float invA = uniformq ? (1.0f / 1024.0f) : (1.0f / lA);
        const size_t ra = (size_t)(b*S_ + q0 + wv*32 + l15);
        #pragma unroll
        for (int dt = 0; dt < 5; dt++) {
            union { bf16 hh[4]; uint2 u; } t4;
            #pragma unroll
            for (int r = 0; r < 4; r++) t4.hh[r] = f2b(oA[dt][r] * invA);
            *(uint2*)&o[ra*E_ + h*D_ + dt*16 + quad*4] = t4.u;
        }
        const float invB = uniformq ? (1.0f / 1024.0f) : (1.0f / lB);
        const size_t rb = ra + 16;
        #pragma unroll
        for (int dt = 0; dt < 5; dt++) {
            union { bf16 hh[4]; uint2 u; } t4;
            #pragma unroll
            for (int r = 0; r < 4; r++) t4.hh[r] = f2b(oB[dt][r] * invB);
            *(uint2*)&o[rb*E_ + h*D_ + dt*16 + quad*4] = t4.u;
        }
    }
}

extern "C" void kernel_launch(void* const* d_in, const int* in_sizes, int n_in,
                              void* d_out, int out_size, void* d_ws, size_t ws_size,
                              hipStream_t stream)
{
    const float* x    = (const float*)d_in[0];
    const int*   cu   = (const int*)  d_in[1];
    const float* cosp = (const float*)d_in[2];
    const float* sinp = (const float*)d_in[3];
    const float* wq   = (const float*)d_in[4];
    const float* bq   = (const float*)d_in[5];
    const float* wk   = (const float*)d_in[6];
    const float* bk   = (const float*)d_in[7];
    const float* wv   = (const float*)d_in[8];
    const float* bv   = (const float*)d_in[9];
    const float* wo   = (const float*)d_in[10];
    const float* bo   = (const float*)d_in[11];
    float* out = (float*)d_out;

    bf16* q   = (bf16*)d_ws;
    bf16* kk  = q   + (size_t)M_ * E_;
    bf16* vt  = kk  + (size_t)M_ * E_;   // transposed V: [B][H][D][S]
    bf16* ao  = vt  + (size_t)M_ * E_;
    bf16* xb  = ao  + (size_t)M_ * E_;
    bf16* wqb = xb  + (size_t)M_ * E_;
    bf16* wkb = wqb + (size_t)E_ * E_;
    bf16* wvb = wkb + (size_t)E_ * E_;
    bf16* wob = wvb + (size_t)E_ * E_;

    // 0) convert x + 4 weight matrices to bf16
    cvt_kernel<<<dim3(2560, 5), 256, 0, stream>>>(
        x, wq, wk, wv, wo, xb, wqb, wkb, wvb, wob, M_*E_, E_*E_);

    // 1) QKV projection: 256x256 8-phase MFMA GEMM (identity block mapping).
    qkv_gemm_8ph<<<dim3(M_/256, 15), 512, 0, stream>>>(
        xb, wqb, wkb, wvb, bq, bk, bv, q, kk, vt);

    // 1.5) one-shot RoPE on q (pre-scaled) and k, in place
    rope_kernel<<<2560, 256, 0, stream>>>(q, kk, cosp, sinp);

    // 2) MFMA flash attention v12b (32 rows/wave, 2 blocks/CU enforced)
    attn_mfma<<<256, 512, 0, stream>>>(q, kk, vt, cu, ao);

    // 3) output projection (swapped-operand 128² MFMA, float4 epilogue)
    oproj_gemm<<<dim3(M_/128, E_/128), 256, 0, stream>>>(ao, wob, bo, out);
}

// Round 8
// 246.622 us; speedup vs baseline: 1.0316x; 1.0316x over previous
//
#include <hip/hip_runtime.h>
#include <hip/hip_bf16.h>

#define B_ 4
#define S_ 1024
#define E_ 1280
#define H_ 16
#define D_ 80
#define M_ (B_*S_)   // 4096

typedef __hip_bfloat16 bf16;
using bf16x8 = __attribute__((ext_vector_type(8))) short;  // 8 bf16 = 4 VGPRs
using f32x4  = __attribute__((ext_vector_type(4))) float;  // MFMA C/D frag

__device__ __forceinline__ float b2f(bf16 x){ return __bfloat162float(x); }
__device__ __forceinline__ bf16  f2b(float x){ return __float2bfloat16(x); }

__device__ __forceinline__ void gload_lds16(const void* g, void* l) {
    __builtin_amdgcn_global_load_lds(
        (const __attribute__((address_space(1))) unsigned int*)g,
        (__attribute__((address_space(3))) unsigned int*)l, 16, 0, 0);
}

// 8-phase sync helpers (rule #18: sched_barrier(0) after inline waitcnt)
__device__ __forceinline__ void ph_begin() {
    __builtin_amdgcn_s_barrier();
    asm volatile("s_waitcnt lgkmcnt(0)" ::: "memory");
    __builtin_amdgcn_sched_barrier(0);
    __builtin_amdgcn_s_setprio(1);
}
__device__ __forceinline__ void ph_end() {
    __builtin_amdgcn_s_setprio(0);
    __builtin_amdgcn_sched_barrier(0);
    __builtin_amdgcn_s_barrier();
}
__device__ __forceinline__ void ph_end_vm6() {
    __builtin_amdgcn_s_setprio(0);
    __builtin_amdgcn_sched_barrier(0);
    asm volatile("s_waitcnt vmcnt(6)" ::: "memory");
    __builtin_amdgcn_s_barrier();
}
__device__ __forceinline__ void ph_end_vm0() {
    __builtin_amdgcn_s_setprio(0);
    __builtin_amdgcn_sched_barrier(0);
    asm volatile("s_waitcnt vmcnt(0)" ::: "memory");
    __builtin_amdgcn_s_barrier();
}

// fp32 -> bf16 conversion, 8 elems/thread. blockIdx.y selects segment.
__global__ __launch_bounds__(256) void cvt_kernel(
    const float* __restrict__ s0, const float* __restrict__ s1,
    const float* __restrict__ s2, const float* __restrict__ s3,
    const float* __restrict__ s4,
    bf16* __restrict__ d0, bf16* __restrict__ d1, bf16* __restrict__ d2,
    bf16* __restrict__ d3, bf16* __restrict__ d4,
    int n0, int n1)
{
    const float* s; bf16* d; int n;
    switch (blockIdx.y) {
        case 0: s = s0; d = d0; n = n0; break;
        case 1: s = s1; d = d1; n = n1; break;
        case 2: s = s2; d = d2; n = n1; break;
        case 3: s = s3; d = d3; n = n1; break;
        default: s = s4; d = d4; n = n1; break;
    }
    int i = (blockIdx.x * 256 + threadIdx.x) * 8;
    if (i >= n) return;
    float4 a = *(const float4*)(s + i);
    float4 b = *(const float4*)(s + i + 4);
    bf16 t[8];
    t[0]=f2b(a.x); t[1]=f2b(a.y); t[2]=f2b(a.z); t[3]=f2b(a.w);
    t[4]=f2b(b.x); t[5]=f2b(b.y); t[6]=f2b(b.z); t[7]=f2b(b.w);
    *(uint4*)(d + i) = *(const uint4*)t;
}

// ============================================================================
// QKV projection: 256x256 8-phase MFMA GEMM (T2+T3+T4+T5). Identity block
// mapping (r6 XCD remap reverted — it made each XCD read ALL of A).
// ============================================================================
__global__ __launch_bounds__(512, 2) void qkv_gemm_8ph(
    const bf16* __restrict__ A,
    const bf16* __restrict__ W0, const bf16* __restrict__ W1, const bf16* __restrict__ W2,
    const float* __restrict__ b0, const float* __restrict__ b1, const float* __restrict__ b2,
    bf16* __restrict__ Cq, bf16* __restrict__ Ck, bf16* __restrict__ Cv)
{
    constexpr int K = 1280;
    constexpr int NITER = K / 128;   // 10 iterations, 2 K-tiles each

    __shared__ __align__(16) bf16 Asm[2][2][128*64];   // [buf][half][row*64+col]
    __shared__ __align__(16) bf16 Bsm[2][2][128*64];

    const int bm  = blockIdx.x * 256;
    const int ny  = blockIdx.y;            // 0..14
    const int mat = ny / 5;
    const int bn  = (ny % 5) * 256;        // col base within matrix
    const bf16*  W    = (mat == 0) ? W0 : (mat == 1) ? W1 : W2;
    const float* bias = (mat == 0) ? b0 : (mat == 1) ? b1 : b2;

    const int tid  = threadIdx.x;
    const int lane = tid & 63, wv = tid >> 6;
    const int wm = wv >> 2, wn = wv & 3;        // wave tile: rows wm*128, cols wn*64
    const int quad = lane >> 4, l15 = lane & 15;

    auto stageA = [&](int j_, int half) {
        #pragma unroll
        for (int i = 0; i < 2; i++) {
            const int c   = tid + i*512;
            const int row = c >> 3;
            const int g   = (c & 7) ^ (row & 7);
            gload_lds16(A + (size_t)(bm + half*128 + row) * K + j_*64 + g*8,
                        &Asm[j_ & 1][half][(wv*64 + i*512) * 8]);
        }
    };
    auto stageB = [&](int j_, int half) {
        #pragma unroll
        for (int i = 0; i < 2; i++) {
            const int c   = tid + i*512;
            const int row = c >> 3;
            const int g   = (c & 7) ^ (row & 7);
            gload_lds16(W + (size_t)(bn + half*128 + row) * K + j_*64 + g*8,
                        &Bsm[j_ & 1][half][(wv*64 + i*512) * 8]);
        }
    };
    auto lda = [&](int bf, int mt, int ks) -> bf16x8 {
        const int r = mt*16 + l15;
        return *(const bf16x8*)&Asm[bf][wm][r*64 + (((quad + ks*4) ^ (r & 7)) << 3)];
    };
    auto ldb = [&](int bf, int nt, int ks) -> bf16x8 {
        const int r = (wn & 1)*64 + nt*16 + l15;
        return *(const bf16x8*)&Bsm[bf][wn >> 1][r*64 + (((quad + ks*4) ^ (r & 7)) << 3)];
    };

    f32x4 acc[8][4] = {};
    bf16x8 a[4][2], bA[2][2], bB[2][2];

#define MFMA_Q(MT0, NT0, BB_) do { \
    _Pragma("unroll") for (int mt_ = 0; mt_ < 4; mt_++) \
    _Pragma("unroll") for (int nt_ = 0; nt_ < 2; nt_++) \
    _Pragma("unroll") for (int ks_ = 0; ks_ < 2; ks_++) \
        acc[(MT0)+mt_][(NT0)+nt_] = __builtin_amdgcn_mfma_f32_16x16x32_bf16( \
            a[mt_][ks_], BB_[nt_][ks_], acc[(MT0)+mt_][(NT0)+nt_], 0, 0, 0); \
} while (0)

    stageA(0, 0); stageA(0, 1); stageB(0, 0); stageB(0, 1);
    stageA(1, 0); stageA(1, 1); stageB(1, 0); stageB(1, 1);
    __syncthreads();

    for (int t = 0; t < NITER; t++) {
        const int  j  = 2*t;
        const bool pf = (t + 1 < NITER);

        #pragma unroll
        for (int mt = 0; mt < 4; mt++) { a[mt][0] = lda(0, mt, 0); a[mt][1] = lda(0, mt, 1); }
        #pragma unroll
        for (int nt = 0; nt < 2; nt++) { bA[nt][0] = ldb(0, nt, 0); bA[nt][1] = ldb(0, nt, 1); }
        stageA(j+1, 1);
        ph_begin(); MFMA_Q(0, 0, bA); ph_end();

        #pragma unroll
        for (int nt = 0; nt < 2; nt++) { bB[nt][0] = ldb(0, 2+nt, 0); bB[nt][1] = ldb(0, 2+nt, 1); }
        ph_begin(); MFMA_Q(0, 2, bB); ph_end();

        #pragma unroll
        for (int mt = 0; mt < 4; mt++) { a[mt][0] = lda(0, 4+mt, 0); a[mt][1] = lda(0, 4+mt, 1); }
        if (pf) stageB(j+2, 0);
        ph_begin(); MFMA_Q(4, 0, bA); ph_end();

        if (pf) { stageB(j+2, 1); stageA(j+2, 0); }
        ph_begin(); MFMA_Q(4, 2, bB);
        if (pf) ph_end_vm6(); else ph_end_vm0();

        #pragma unroll
        for (int mt = 0; mt < 4; mt++) { a[mt][0] = lda(1, mt, 0); a[mt][1] = lda(1, mt, 1); }
        #pragma unroll
        for (int nt = 0; nt < 2; nt++) { bA[nt][0] = ldb(1, nt, 0); bA[nt][1] = ldb(1, nt, 1); }
        if (pf) stageA(j+2, 1);
        ph_begin(); MFMA_Q(0, 0, bA); ph_end();

        #pragma unroll
        for (int nt = 0; nt < 2; nt++) { bB[nt][0] = ldb(1, 2+nt, 0); bB[nt][1] = ldb(1, 2+nt, 1); }
        ph_begin(); MFMA_Q(0, 2, bB); ph_end();

        #pragma unroll
        for (int mt = 0; mt < 4; mt++) { a[mt][0] = lda(1, 4+mt, 0); a[mt][1] = lda(1, 4+mt, 1); }
        if (pf) stageB(j+3, 0);
        ph_begin(); MFMA_Q(4, 0, bA); ph_end();

        if (pf) { stageB(j+3, 1); stageA(j+3, 0); }
        ph_begin(); MFMA_Q(4, 2, bB); ph_end_vm6();
    }
#undef MFMA_Q

    if (mat < 2) {
        bf16* C = (mat == 0) ? Cq : Ck;
        #pragma unroll
        for (int nt = 0; nt < 4; nt++) {
            const int ncol = bn + wn*64 + nt*16 + l15;
            const float bv = bias[ncol];
            #pragma unroll
            for (int mt = 0; mt < 8; mt++) {
                const int m0 = bm + wm*128 + mt*16 + quad*4;
                #pragma unroll
                for (int r = 0; r < 4; r++)
                    C[(size_t)(m0 + r) * E_ + ncol] = f2b(acc[mt][nt][r] + bv);
            }
        }
    } else {
        #pragma unroll
        for (int nt = 0; nt < 4; nt++) {
            const int ncol = bn + wn*64 + nt*16 + l15;
            const float bv = bias[ncol];
            const int hh = ncol / 80, dd = ncol % 80;
            #pragma unroll
            for (int mt = 0; mt < 8; mt++) {
                const int m0  = bm + wm*128 + mt*16 + quad*4;
                const int btok = m0 >> 10;
                const int key  = m0 & 1023;
                union { bf16 h[4]; uint2 u; } t4;
                #pragma unroll
                for (int r = 0; r < 4; r++) t4.h[r] = f2b(acc[mt][nt][r] + bv);
                *(uint2*)&Cv[((size_t)(btok*H_ + hh)*D_ + dd)*S_ + key] = t4.u;
            }
        }
    }
}

// ============================================================================
// Output projection: 128x128 m97-style GEMM, swapped MFMA operands ->
// float4 epilogue (lane owns row l15 x 4 consecutive cols).
// ============================================================================
__global__ __launch_bounds__(256) void oproj_gemm(
    const bf16* __restrict__ A, const bf16* __restrict__ W,
    const float* __restrict__ bias, float* __restrict__ C)
{
    const int K = E_, N = E_;
    const int bn = blockIdx.y * 128;
    const int bm = blockIdx.x * 128;

    __shared__ bf16 As[2][128][32];
    __shared__ bf16 Ws[2][128][32];

    const int tid  = threadIdx.x;
    const int lane = tid & 63;
    const int wv   = tid >> 6;
    const int wm   = (wv & 1) * 64;
    const int wn   = (wv >> 1) * 64;
    const int srow = wv * 16 + (lane >> 2);
    const int scol = (lane & 3) * 8;

    f32x4 acc[4][4] = {};

    for (int k0 = 0; k0 < K; k0 += 64) {
        __syncthreads();
        #pragma unroll
        for (int p = 0; p < 2; p++) {
            const int kc = k0 + p*32 + scol;
            gload_lds16(A + (size_t)(bm + srow)      * K + kc, &As[p][wv*16][0]);
            gload_lds16(A + (size_t)(bm + 64 + srow) * K + kc, &As[p][64 + wv*16][0]);
            gload_lds16(W + (size_t)(bn + srow)      * K + kc, &Ws[p][wv*16][0]);
            gload_lds16(W + (size_t)(bn + 64 + srow) * K + kc, &Ws[p][64 + wv*16][0]);
        }
        __syncthreads();

        const int fr = lane & 15;
        const int kq = (lane >> 4) * 8;
        #pragma unroll
        for (int p = 0; p < 2; p++) {
            bf16x8 af[4], wf[4];
            #pragma unroll
            for (int t = 0; t < 4; t++) {
                af[t] = *(const bf16x8*)&As[p][wm + t*16 + fr][kq];
                wf[t] = *(const bf16x8*)&Ws[p][wn + t*16 + fr][kq];
            }
            #pragma unroll
            for (int mt = 0; mt < 4; mt++)
                #pragma unroll
                for (int nt = 0; nt < 4; nt++)
                    acc[mt][nt] = __builtin_amdgcn_mfma_f32_16x16x32_bf16(
                        wf[nt], af[mt], acc[mt][nt], 0, 0, 0);   // SWAPPED
        }
    }

    const int l15  = lane & 15;
    const int quad = lane >> 4;
    #pragma unroll
    for (int nt = 0; nt < 4; nt++) {
        const int n0 = bn + wn + nt*16 + quad*4;
        const float4 bv4 = *(const float4*)&bias[n0];
        #pragma unroll
        for (int mt = 0; mt < 4; mt++) {
            const int m = bm + wm + mt*16 + l15;
            float4 o4;
            o4.x = acc[mt][nt][0] + bv4.x;
            o4.y = acc[mt][nt][1] + bv4.y;
            o4.z = acc[mt][nt][2] + bv4.z;
            o4.w = acc[mt][nt][3] + bv4.w;
            *(float4*)&C[(size_t)m * N + n0] = o4;
        }
    }
}

// rope helper
__device__ __forceinline__ void rope8(const bf16* lo, const bf16* hi,
                                      const float* cp, const float* sp,
                                      float mul, uint4* out_lo, uint4* out_hi)
{
    union { uint4 u; bf16 h[8]; } li, hi_, lo_o, hi_o;
    li.u  = *(const uint4*)lo;
    hi_.u = *(const uint4*)hi;
    #pragma unroll
    for (int u = 0; u < 8; u++) {
        float x1 = b2f(li.h[u]), x2 = b2f(hi_.h[u]);
        float c = cp[u], s = sp[u];
        lo_o.h[u] = f2b((x1*c - x2*s) * mul);
        hi_o.h[u] = f2b((x2*c + x1*s) * mul);
    }
    *out_lo = lo_o.u;
    *out_hi = hi_o.u;
}

// One-shot in-place RoPE over q and k. Q additionally pre-scaled by 1/sqrt(80).
__global__ __launch_bounds__(256) void rope_kernel(
    bf16* __restrict__ qp, bf16* __restrict__ kp,
    const float* __restrict__ cosp, const float* __restrict__ sinp)
{
    int idx = blockIdx.x * 256 + threadIdx.x;
    const int NT = M_ * H_ * 5;   // 327680
    bf16* base; float mul;
    if (idx < NT) { base = qp; mul = 0.11180339887498949f; }
    else         { base = kp; mul = 1.0f; idx -= NT; }
    const int row = idx / 80;
    const int rem = idx - row * 80;
    const int h   = rem / 5;
    const int pc  = rem - h * 5;
    const int s   = row & (S_ - 1);
    bf16* p = base + (size_t)row * E_ + h * D_ + pc * 8;
    const float* cp = cosp + s * D_ + pc * 8;
    const float* sp = sinp + s * D_ + pc * 8;
    uint4 olo, ohi;
    rope8(p, p + 40, cp, sp, mul, &olo, &ohi);
    *(uint4*)p        = olo;
    *(uint4*)(p + 40) = ohi;
}

// ============================================================================
// MFMA flash attention v13 — 2 q-groups/wave WITHOUT the r7 mistakes:
//  - 256 threads (4 waves x 32 q-rows = 128-row supertile), grid 512 ->
//    2 blocks/CU (TLP restored; r7's grid 256 = 1 block/CU).
//  - __launch_bounds__(256,4): empirical VGPR cap = 2048/(4*4) = 128
//    (r7's (512,4) capped at 64 -> spill, WRITE 15.4 MB).
//  - PT row stride 64 -> 72 elems (144 B = 36 banks): rows shift 4 banks,
//    P-frag b128 reads go 8-way -> ~2-way (free), writes 4-way -> ~2-way.
//  - DS ops/CU/tile-round: v11 448 -> v13 272 at equal MFMA work.
// LDS: 20480 (K dbuf) + 20480 (V dbuf) + 4*2*2304 (PT) = 59392 B.
// ============================================================================
__global__ __launch_bounds__(256, 4) void attn_mfma(
    const bf16* __restrict__ q, const bf16* __restrict__ k, const bf16* __restrict__ vt,
    const int* __restrict__ cu, bf16* __restrict__ o)
{
    __shared__ __align__(16) bf16 Ks[2][64*80];      // swizzled
    __shared__ __align__(16) bf16 VTs[2][80*64];     // swizzled
    __shared__ __align__(16) bf16 PTq[4][2][16*72];  // per-wave, per-group P

    const int n  = blockIdx.x;                 // 512 blocks
    const int g  = ((n >> 6) << 3) | (n & 7);  // (b,h): XCD = n&7 = h&7
    const int qs = (n >> 3) & 7;               // q-supertile 0..7 (128 rows)
    const int b  = g >> 4;
    const int h  = g & 15;

    const int tid  = threadIdx.x;              // 0..255
    const int lane = tid & 63, wv = tid >> 6;  // wv 0..3
    const int quad = lane >> 4, l15 = lane & 15;
    const int q0   = qs * 128;
    const int len  = cu[b + 1] - cu[b];

    const bool uniformq = (q0 >= len);
    const bool fast     = !uniformq && ((q0 + 128) <= len) && ((len & 63) == 0);
    const int  ktiles   = uniformq ? 16 : (fast ? (len >> 6) : 16);
    const bool domask   = !uniformq && !fast;

    bf16* PTa = &PTq[wv][0][0];
    bf16* PTb = &PTq[wv][1][0];

    // Q fragments (B-operand): two query groups, rows q0+wv*32+l15 and +16.
    bf16x8 qfA[3] = {}, qfB[3] = {};
    if (!uniformq) {
        const bf16* qra = q + (size_t)(b*S_ + q0 + wv*32 + l15)*E_ + h*D_ + quad*8;
        qfA[0] = *(const bf16x8*)(qra);
        qfA[1] = *(const bf16x8*)(qra + 32);
        if (quad < 2) qfA[2] = *(const bf16x8*)(qra + 64);
        const bf16* qrb = qra + (size_t)16 * E_;
        qfB[0] = *(const bf16x8*)(qrb);
        qfB[1] = *(const bf16x8*)(qrb + 32);
        if (quad < 2) qfB[2] = *(const bf16x8*)(qrb + 64);
    }

    float mA = -1e30f, lA = 0.f, mB = -1e30f, lB = 0.f;
    f32x4 oA[5] = {}, oB[5] = {};

    bf16x8 pone;
    {
        const short one_s = (short)0x3F80;   // bf16 1.0
        #pragma unroll
        for (int i = 0; i < 8; i++) pone[i] = one_s;
    }

    const int u_  = l15 >> 2;
    const int s0r = quad ^ u_;            // K granule ks=0
    const int sv0 = quad ^ (l15 & 7);     // V granule ks=0

    // staging: chunks 0..639 = K tile, 640..1279 = V tile; 5 iters x 256 thr.
    auto stage = [&](int kt, int bf) {
        #pragma unroll
        for (int i = 0; i < 5; i++) {
            int c = tid + i * 256;        // 0..1279
            if (c < 640) {
                if (!uniformq) {
                    int row = c / 10, s5 = c - row * 10;
                    int uu = (row >> 2) & 3;
                    int sg = (s5 < 8) ? (s5 ^ uu) : (8 + ((s5 ^ uu) & 1));
                    gload_lds16(k + (size_t)(b*S_ + kt*64 + row)*E_ + h*D_ + sg*8,
                                &Ks[bf][c*8]);
                }
            } else {
                int c2 = c - 640;
                int row = c2 >> 3, s5 = c2 & 7;
                int sg = s5 ^ (row & 7);
                gload_lds16(vt + ((size_t)(b*H_ + h)*D_ + row)*S_ + kt*64 + sg*8,
                            &VTs[bf][c2*8]);
            }
        }
    };

    stage(0, 0);
    __syncthreads();   // buf0 ready

    // per-group online softmax + P-write (PT stride 72)
    auto softmax_pt = [&](f32x4* s4, float& m_s, float& l_s, f32x4* oc,
                          bf16* PTg, bool vq, int kt) {
        float sv[4][4];
        if (!domask) {
            #pragma unroll
            for (int nt = 0; nt < 4; nt++)
                #pragma unroll
                for (int r = 0; r < 4; r++)
                    sv[nt][r] = s4[nt][r];
        } else {
            #pragma unroll
            for (int nt = 0; nt < 4; nt++)
                #pragma unroll
                for (int r = 0; r < 4; r++) {
                    const bool vk = (kt*64 + nt*16 + quad*4 + r) < len;
                    sv[nt][r] = (vq && vk) ? s4[nt][r] : -1e9f;
                }
        }
        float rm[4];
        #pragma unroll
        for (int nt = 0; nt < 4; nt++)
            rm[nt] = fmaxf(fmaxf(sv[nt][0], sv[nt][1]), fmaxf(sv[nt][2], sv[nt][3]));
        float sloc = fmaxf(fmaxf(rm[0], rm[1]), fmaxf(rm[2], rm[3]));
        sloc = fmaxf(sloc, __shfl_xor(sloc, 16, 64));
        sloc = fmaxf(sloc, __shfl_xor(sloc, 32, 64));
        const float mnew  = fmaxf(m_s, sloc);
        const float alpha = __expf(m_s - mnew);
        float p[4][4], lsum = 0.f;
        #pragma unroll
        for (int nt = 0; nt < 4; nt++)
            #pragma unroll
            for (int r = 0; r < 4; r++) {
                p[nt][r] = __expf(sv[nt][r] - mnew);
                lsum += p[nt][r];
            }
        lsum += __shfl_xor(lsum, 16, 64);
        lsum += __shfl_xor(lsum, 32, 64);
        l_s = l_s * alpha + lsum;
        m_s = mnew;
        #pragma unroll
        for (int dt = 0; dt < 5; dt++)
            #pragma unroll
            for (int r = 0; r < 4; r++)
                oc[dt][r] *= alpha;
        #pragma unroll
        for (int nt = 0; nt < 4; nt++) {
            union { bf16 hh[4]; uint2 u; } w;
            #pragma unroll
            for (int r = 0; r < 4; r++) w.hh[r] = f2b(p[nt][r]);
            const int gw = (2*nt + (quad >> 1)) ^ (l15 & 7);
            *(uint2*)&PTg[l15*72 + gw*8 + (quad & 1)*4] = w.u;
        }
    };

    for (int kt = 0; kt < ktiles; kt++) {
        const int cur = kt & 1;
        if (kt + 1 < ktiles) stage(kt + 1, cur ^ 1);   // loads fly during compute

        bf16x8 pfA0 = pone, pfA1 = pone, pfB0 = pone, pfB1 = pone;
        if (!uniformq) {
            // ---- QK^T swapped: A=K, B=Q; K frags shared by both query groups
            f32x4 sa[4], sb[4];
            #pragma unroll
            for (int nt = 0; nt < 4; nt++) {
                const bf16* kr = &Ks[cur][(nt*16 + l15) * 80];
                bf16x8 kf0 = *(const bf16x8*)(kr + s0r*8);
                bf16x8 kf1 = *(const bf16x8*)(kr + 32 + s0r*8);
                bf16x8 kf2 = {};
                if (quad < 2) kf2 = *(const bf16x8*)(kr + 64 + (s0r & 1)*8);
                f32x4 a0 = {}, b0 = {};
                a0 = __builtin_amdgcn_mfma_f32_16x16x32_bf16(kf0, qfA[0], a0, 0, 0, 0);
                a0 = __builtin_amdgcn_mfma_f32_16x16x32_bf16(kf1, qfA[1], a0, 0, 0, 0);
                a0 = __builtin_amdgcn_mfma_f32_16x16x32_bf16(kf2, qfA[2], a0, 0, 0, 0);
                b0 = __builtin_amdgcn_mfma_f32_16x16x32_bf16(kf0, qfB[0], b0, 0, 0, 0);
                b0 = __builtin_amdgcn_mfma_f32_16x16x32_bf16(kf1, qfB[1], b0, 0, 0, 0);
                b0 = __builtin_amdgcn_mfma_f32_16x16x32_bf16(kf2, qfB[2], b0, 0, 0, 0);
                sa[nt] = a0; sb[nt] = b0;
            }

            const bool vqA = (q0 + wv*32 + l15) < len;
            const bool vqB = (q0 + wv*32 + 16 + l15) < len;
            softmax_pt(sa, mA, lA, oA, PTa, vqA, kt);
            softmax_pt(sb, mB, lB, oB, PTb, vqB, kt);

            // P-frags (same-wave RAW via lgkmcnt), stride-72 rows
            pfA0 = *(const bf16x8*)&PTa[l15*72 + ((quad    ) ^ (l15 & 7))*8];
            pfA1 = *(const bf16x8*)&PTa[l15*72 + ((quad + 4) ^ (l15 & 7))*8];
            pfB0 = *(const bf16x8*)&PTb[l15*72 + ((quad    ) ^ (l15 & 7))*8];
            pfB1 = *(const bf16x8*)&PTb[l15*72 + ((quad + 4) ^ (l15 & 7))*8];
        }

        // ---- PV: V frags shared by both groups
        #pragma unroll
        for (int dt = 0; dt < 5; dt++) {
            const bf16* vr = &VTs[cur][(dt*16 + l15) * 64];
            bf16x8 vf0 = *(const bf16x8*)(vr + sv0*8);
            bf16x8 vf1 = *(const bf16x8*)(vr + (sv0 ^ 4)*8);
            oA[dt] = __builtin_amdgcn_mfma_f32_16x16x32_bf16(vf0, pfA0, oA[dt], 0, 0, 0);
            oA[dt] = __builtin_amdgcn_mfma_f32_16x16x32_bf16(vf1, pfA1, oA[dt], 0, 0, 0);
            oB[dt] = __builtin_amdgcn_mfma_f32_16x16x32_bf16(vf0, pfB0, oB[dt], 0, 0, 0);
            oB[dt] = __builtin_amdgcn_mfma_f32_16x16x32_bf16(vf1, pfB1, oB[dt], 0, 0, 0);
        }
        __syncthreads();   // reads of buf[cur] done; buf[cur^1] loads drained
    }

    // ---- epilogue: group A row, group B row (+16)
    {
        const float invA = uniformq ? (1.0f / 1024.0f) : (1.0f / lA);
        const size_t ra = (size_t)(b*S_ + q0 + wv*32 + l15);
        #pragma unroll
        for (int dt = 0; dt < 5; dt++) {
            union { bf16 hh[4]; uint2 u; } t4;
            #pragma unroll
            for (int r = 0; r < 4; r++) t4.hh[r] = f2b(oA[dt][r] * invA);
            *(uint2*)&o[ra*E_ + h*D_ + dt*16 + quad*4] = t4.u;
        }
        const float invB = uniformq ? (1.0f / 1024.0f) : (1.0f / lB);
        const size_t rb = ra + 16;
        #pragma unroll
        for (int dt = 0; dt < 5; dt++) {
            union { bf16 hh[4]; uint2 u; } t4;
            #pragma unroll
            for (int r = 0; r < 4; r++) t4.hh[r] = f2b(oB[dt][r] * invB);
            *(uint2*)&o[rb*E_ + h*D_ + dt*16 + quad*4] = t4.u;
        }
    }
}

extern "C" void kernel_launch(void* const* d_in, const int* in_sizes, int n_in,
                              void* d_out, int out_size, void* d_ws, size_t ws_size,
                              hipStream_t stream)
{
    const float* x    = (const float*)d_in[0];
    const int*   cu   = (const int*)  d_in[1];
    const float* cosp = (const float*)d_in[2];
    const float* sinp = (const float*)d_in[3];
    const float* wq   = (const float*)d_in[4];
    const float* bq   = (const float*)d_in[5];
    const float* wk   = (const float*)d_in[6];
    const float* bk   = (const float*)d_in[7];
    const float* wv   = (const float*)d_in[8];
    const float* bv   = (const float*)d_in[9];
    const float* wo   = (const float*)d_in[10];
    const float* bo   = (const float*)d_in[11];
    float* out = (float*)d_out;

    bf16* q   = (bf16*)d_ws;
    bf16* kk  = q   + (size_t)M_ * E_;
    bf16* vt  = kk  + (size_t)M_ * E_;   // transposed V: [B][H][D][S]
    bf16* ao  = vt  + (size_t)M_ * E_;
    bf16* xb  = ao  + (size_t)M_ * E_;
    bf16* wqb = xb  + (size_t)M_ * E_;
    bf16* wkb = wqb + (size_t)E_ * E_;
    bf16* wvb = wkb + (size_t)E_ * E_;
    bf16* wob = wvb + (size_t)E_ * E_;

    // 0) convert x + 4 weight matrices to bf16
    cvt_kernel<<<dim3(2560, 5), 256, 0, stream>>>(
        x, wq, wk, wv, wo, xb, wqb, wkb, wvb, wob, M_*E_, E_*E_);

    // 1) QKV projection: 256x256 8-phase MFMA GEMM (identity block mapping).
    qkv_gemm_8ph<<<dim3(M_/256, 15), 512, 0, stream>>>(
        xb, wqb, wkb, wvb, bq, bk, bv, q, kk, vt);

    // 1.5) one-shot RoPE on q (pre-scaled) and k, in place
    rope_kernel<<<2560, 256, 0, stream>>>(q, kk, cosp, sinp);

    // 2) MFMA flash attention v13 (4 waves x 32 rows, 2 blocks/CU, PT pad)
    attn_mfma<<<512, 256, 0, stream>>>(q, kk, vt, cu, ao);

    // 3) output projection (swapped-operand 128² MFMA, float4 epilogue)
    oproj_gemm<<<dim3(M_/128, E_/128), 256, 0, stream>>>(ao, wob, bo, out);
}

// Round 9
// 240.393 us; speedup vs baseline: 1.0583x; 1.0259x over previous
//
#include <hip/hip_runtime.h>
#include <hip/hip_bf16.h>

#define B_ 4
#define S_ 1024
#define E_ 1280
#define H_ 16
#define D_ 80
#define M_ (B_*S_)   // 4096

typedef __hip_bfloat16 bf16;
using bf16x8 = __attribute__((ext_vector_type(8))) short;  // 8 bf16 = 4 VGPRs
using f32x4  = __attribute__((ext_vector_type(4))) float;  // MFMA C/D frag

__device__ __forceinline__ float b2f(bf16 x){ return __bfloat162float(x); }
__device__ __forceinline__ bf16  f2b(float x){ return __float2bfloat16(x); }

__device__ __forceinline__ void gload_lds16(const void* g, void* l) {
    __builtin_amdgcn_global_load_lds(
        (const __attribute__((address_space(1))) unsigned int*)g,
        (__attribute__((address_space(3))) unsigned int*)l, 16, 0, 0);
}

// 8-phase sync helpers (rule #18: sched_barrier(0) after inline waitcnt)
__device__ __forceinline__ void ph_begin() {
    __builtin_amdgcn_s_barrier();
    asm volatile("s_waitcnt lgkmcnt(0)" ::: "memory");
    __builtin_amdgcn_sched_barrier(0);
    __builtin_amdgcn_s_setprio(1);
}
__device__ __forceinline__ void ph_end() {
    __builtin_amdgcn_s_setprio(0);
    __builtin_amdgcn_sched_barrier(0);
    __builtin_amdgcn_s_barrier();
}
__device__ __forceinline__ void ph_end_vm6() {
    __builtin_amdgcn_s_setprio(0);
    __builtin_amdgcn_sched_barrier(0);
    asm volatile("s_waitcnt vmcnt(6)" ::: "memory");
    __builtin_amdgcn_s_barrier();
}
__device__ __forceinline__ void ph_end_vm0() {
    __builtin_amdgcn_s_setprio(0);
    __builtin_amdgcn_sched_barrier(0);
    asm volatile("s_waitcnt vmcnt(0)" ::: "memory");
    __builtin_amdgcn_s_barrier();
}

// fp32 -> bf16 conversion, 8 elems/thread. blockIdx.y selects segment.
__global__ __launch_bounds__(256) void cvt_kernel(
    const float* __restrict__ s0, const float* __restrict__ s1,
    const float* __restrict__ s2, const float* __restrict__ s3,
    const float* __restrict__ s4,
    bf16* __restrict__ d0, bf16* __restrict__ d1, bf16* __restrict__ d2,
    bf16* __restrict__ d3, bf16* __restrict__ d4,
    int n0, int n1)
{
    const float* s; bf16* d; int n;
    switch (blockIdx.y) {
        case 0: s = s0; d = d0; n = n0; break;
        case 1: s = s1; d = d1; n = n1; break;
        case 2: s = s2; d = d2; n = n1; break;
        case 3: s = s3; d = d3; n = n1; break;
        default: s = s4; d = d4; n = n1; break;
    }
    int i = (blockIdx.x * 256 + threadIdx.x) * 8;
    if (i >= n) return;
    float4 a = *(const float4*)(s + i);
    float4 b = *(const float4*)(s + i + 4);
    bf16 t[8];
    t[0]=f2b(a.x); t[1]=f2b(a.y); t[2]=f2b(a.z); t[3]=f2b(a.w);
    t[4]=f2b(b.x); t[5]=f2b(b.y); t[6]=f2b(b.z); t[7]=f2b(b.w);
    *(uint4*)(d + i) = *(const uint4*)t;
}

// ============================================================================
// QKV projection: 256x256 8-phase MFMA GEMM (T2+T3+T4+T5). Identity block
// mapping. Unchanged from r8 (measured 54-55 µs).
// ============================================================================
__global__ __launch_bounds__(512, 2) void qkv_gemm_8ph(
    const bf16* __restrict__ A,
    const bf16* __restrict__ W0, const bf16* __restrict__ W1, const bf16* __restrict__ W2,
    const float* __restrict__ b0, const float* __restrict__ b1, const float* __restrict__ b2,
    bf16* __restrict__ Cq, bf16* __restrict__ Ck, bf16* __restrict__ Cv)
{
    constexpr int K = 1280;
    constexpr int NITER = K / 128;   // 10 iterations, 2 K-tiles each

    __shared__ __align__(16) bf16 Asm[2][2][128*64];   // [buf][half][row*64+col]
    __shared__ __align__(16) bf16 Bsm[2][2][128*64];

    const int bm  = blockIdx.x * 256;
    const int ny  = blockIdx.y;            // 0..14
    const int mat = ny / 5;
    const int bn  = (ny % 5) * 256;        // col base within matrix
    const bf16*  W    = (mat == 0) ? W0 : (mat == 1) ? W1 : W2;
    const float* bias = (mat == 0) ? b0 : (mat == 1) ? b1 : b2;

    const int tid  = threadIdx.x;
    const int lane = tid & 63, wv = tid >> 6;
    const int wm = wv >> 2, wn = wv & 3;        // wave tile: rows wm*128, cols wn*64
    const int quad = lane >> 4, l15 = lane & 15;

    auto stageA = [&](int j_, int half) {
        #pragma unroll
        for (int i = 0; i < 2; i++) {
            const int c   = tid + i*512;
            const int row = c >> 3;
            const int g   = (c & 7) ^ (row & 7);
            gload_lds16(A + (size_t)(bm + half*128 + row) * K + j_*64 + g*8,
                        &Asm[j_ & 1][half][(wv*64 + i*512) * 8]);
        }
    };
    auto stageB = [&](int j_, int half) {
        #pragma unroll
        for (int i = 0; i < 2; i++) {
            const int c   = tid + i*512;
            const int row = c >> 3;
            const int g   = (c & 7) ^ (row & 7);
            gload_lds16(W + (size_t)(bn + half*128 + row) * K + j_*64 + g*8,
                        &Bsm[j_ & 1][half][(wv*64 + i*512) * 8]);
        }
    };
    auto lda = [&](int bf, int mt, int ks) -> bf16x8 {
        const int r = mt*16 + l15;
        return *(const bf16x8*)&Asm[bf][wm][r*64 + (((quad + ks*4) ^ (r & 7)) << 3)];
    };
    auto ldb = [&](int bf, int nt, int ks) -> bf16x8 {
        const int r = (wn & 1)*64 + nt*16 + l15;
        return *(const bf16x8*)&Bsm[bf][wn >> 1][r*64 + (((quad + ks*4) ^ (r & 7)) << 3)];
    };

    f32x4 acc[8][4] = {};
    bf16x8 a[4][2], bA[2][2], bB[2][2];

#define MFMA_Q(MT0, NT0, BB_) do { \
    _Pragma("unroll") for (int mt_ = 0; mt_ < 4; mt_++) \
    _Pragma("unroll") for (int nt_ = 0; nt_ < 2; nt_++) \
    _Pragma("unroll") for (int ks_ = 0; ks_ < 2; ks_++) \
        acc[(MT0)+mt_][(NT0)+nt_] = __builtin_amdgcn_mfma_f32_16x16x32_bf16( \
            a[mt_][ks_], BB_[nt_][ks_], acc[(MT0)+mt_][(NT0)+nt_], 0, 0, 0); \
} while (0)

    stageA(0, 0); stageA(0, 1); stageB(0, 0); stageB(0, 1);
    stageA(1, 0); stageA(1, 1); stageB(1, 0); stageB(1, 1);
    __syncthreads();

    for (int t = 0; t < NITER; t++) {
        const int  j  = 2*t;
        const bool pf = (t + 1 < NITER);

        #pragma unroll
        for (int mt = 0; mt < 4; mt++) { a[mt][0] = lda(0, mt, 0); a[mt][1] = lda(0, mt, 1); }
        #pragma unroll
        for (int nt = 0; nt < 2; nt++) { bA[nt][0] = ldb(0, nt, 0); bA[nt][1] = ldb(0, nt, 1); }
        stageA(j+1, 1);
        ph_begin(); MFMA_Q(0, 0, bA); ph_end();

        #pragma unroll
        for (int nt = 0; nt < 2; nt++) { bB[nt][0] = ldb(0, 2+nt, 0); bB[nt][1] = ldb(0, 2+nt, 1); }
        ph_begin(); MFMA_Q(0, 2, bB); ph_end();

        #pragma unroll
        for (int mt = 0; mt < 4; mt++) { a[mt][0] = lda(0, 4+mt, 0); a[mt][1] = lda(0, 4+mt, 1); }
        if (pf) stageB(j+2, 0);
        ph_begin(); MFMA_Q(4, 0, bA); ph_end();

        if (pf) { stageB(j+2, 1); stageA(j+2, 0); }
        ph_begin(); MFMA_Q(4, 2, bB);
        if (pf) ph_end_vm6(); else ph_end_vm0();

        #pragma unroll
        for (int mt = 0; mt < 4; mt++) { a[mt][0] = lda(1, mt, 0); a[mt][1] = lda(1, mt, 1); }
        #pragma unroll
        for (int nt = 0; nt < 2; nt++) { bA[nt][0] = ldb(1, nt, 0); bA[nt][1] = ldb(1, nt, 1); }
        if (pf) stageA(j+2, 1);
        ph_begin(); MFMA_Q(0, 0, bA); ph_end();

        #pragma unroll
        for (int nt = 0; nt < 2; nt++) { bB[nt][0] = ldb(1, 2+nt, 0); bB[nt][1] = ldb(1, 2+nt, 1); }
        ph_begin(); MFMA_Q(0, 2, bB); ph_end();

        #pragma unroll
        for (int mt = 0; mt < 4; mt++) { a[mt][0] = lda(1, 4+mt, 0); a[mt][1] = lda(1, 4+mt, 1); }
        if (pf) stageB(j+3, 0);
        ph_begin(); MFMA_Q(4, 0, bA); ph_end();

        if (pf) { stageB(j+3, 1); stageA(j+3, 0); }
        ph_begin(); MFMA_Q(4, 2, bB); ph_end_vm6();
    }
#undef MFMA_Q

    if (mat < 2) {
        bf16* C = (mat == 0) ? Cq : Ck;
        #pragma unroll
        for (int nt = 0; nt < 4; nt++) {
            const int ncol = bn + wn*64 + nt*16 + l15;
            const float bv = bias[ncol];
            #pragma unroll
            for (int mt = 0; mt < 8; mt++) {
                const int m0 = bm + wm*128 + mt*16 + quad*4;
                #pragma unroll
                for (int r = 0; r < 4; r++)
                    C[(size_t)(m0 + r) * E_ + ncol] = f2b(acc[mt][nt][r] + bv);
            }
        }
    } else {
        #pragma unroll
        for (int nt = 0; nt < 4; nt++) {
            const int ncol = bn + wn*64 + nt*16 + l15;
            const float bv = bias[ncol];
            const int hh = ncol / 80, dd = ncol % 80;
            #pragma unroll
            for (int mt = 0; mt < 8; mt++) {
                const int m0  = bm + wm*128 + mt*16 + quad*4;
                const int btok = m0 >> 10;
                const int key  = m0 & 1023;
                union { bf16 h[4]; uint2 u; } t4;
                #pragma unroll
                for (int r = 0; r < 4; r++) t4.h[r] = f2b(acc[mt][nt][r] + bv);
                *(uint2*)&Cv[((size_t)(btok*H_ + hh)*D_ + dd)*S_ + key] = t4.u;
            }
        }
    }
}

// ============================================================================
// Output projection: r5's m97-style 128x128 GEMM (UNSWAPPED operands, r5's
// scalar-store epilogue — 16 consecutive cols x 2B = 32 B contiguous per
// quarter-wave beats r8's scattered per-lane float4 stores). Single-matrix
// trim of the old template.
// ============================================================================
__global__ __launch_bounds__(256) void oproj_gemm(
    const bf16* __restrict__ A, const bf16* __restrict__ W,
    const float* __restrict__ bias, float* __restrict__ C)
{
    const int K = E_, N = E_;
    const int bn = blockIdx.y * 128;
    const int bm = blockIdx.x * 128;

    __shared__ bf16 As[2][128][32];
    __shared__ bf16 Ws[2][128][32];

    const int tid  = threadIdx.x;
    const int lane = tid & 63;
    const int wv   = tid >> 6;
    const int wm   = (wv & 1) * 64;
    const int wn   = (wv >> 1) * 64;
    const int srow = wv * 16 + (lane >> 2);
    const int scol = (lane & 3) * 8;

    f32x4 acc[4][4] = {};

    for (int k0 = 0; k0 < K; k0 += 64) {
        __syncthreads();
        #pragma unroll
        for (int p = 0; p < 2; p++) {
            const int kc = k0 + p*32 + scol;
            gload_lds16(A + (size_t)(bm + srow)      * K + kc, &As[p][wv*16][0]);
            gload_lds16(A + (size_t)(bm + 64 + srow) * K + kc, &As[p][64 + wv*16][0]);
            gload_lds16(W + (size_t)(bn + srow)      * K + kc, &Ws[p][wv*16][0]);
            gload_lds16(W + (size_t)(bn + 64 + srow) * K + kc, &Ws[p][64 + wv*16][0]);
        }
        __syncthreads();

        const int fr = lane & 15;
        const int kq = (lane >> 4) * 8;
        #pragma unroll
        for (int p = 0; p < 2; p++) {
            bf16x8 af[4], wf[4];
            #pragma unroll
            for (int t = 0; t < 4; t++) {
                af[t] = *(const bf16x8*)&As[p][wm + t*16 + fr][kq];
                wf[t] = *(const bf16x8*)&Ws[p][wn + t*16 + fr][kq];
            }
            #pragma unroll
            for (int mt = 0; mt < 4; mt++)
                #pragma unroll
                for (int nt = 0; nt < 4; nt++)
                    acc[mt][nt] = __builtin_amdgcn_mfma_f32_16x16x32_bf16(
                        af[mt], wf[nt], acc[mt][nt], 0, 0, 0);
        }
    }

    const int col_l = lane & 15;
    const int row_l = (lane >> 4) * 4;
    #pragma unroll
    for (int nt = 0; nt < 4; nt++) {
        const int n = bn + wn + nt*16 + col_l;
        const float bv = bias[n];
        #pragma unroll
        for (int mt = 0; mt < 4; mt++) {
            #pragma unroll
            for (int r = 0; r < 4; r++) {
                const int m = bm + wm + mt*16 + row_l + r;
                C[(size_t)m * N + n] = acc[mt][nt][r] + bv;
            }
        }
    }
}

// rope helper
__device__ __forceinline__ void rope8(const bf16* lo, const bf16* hi,
                                      const float* cp, const float* sp,
                                      float mul, uint4* out_lo, uint4* out_hi)
{
    union { uint4 u; bf16 h[8]; } li, hi_, lo_o, hi_o;
    li.u  = *(const uint4*)lo;
    hi_.u = *(const uint4*)hi;
    #pragma unroll
    for (int u = 0; u < 8; u++) {
        float x1 = b2f(li.h[u]), x2 = b2f(hi_.h[u]);
        float c = cp[u], s = sp[u];
        lo_o.h[u] = f2b((x1*c - x2*s) * mul);
        hi_o.h[u] = f2b((x2*c + x1*s) * mul);
    }
    *out_lo = lo_o.u;
    *out_hi = hi_o.u;
}

// One-shot in-place RoPE over q and k. Q additionally pre-scaled by 1/sqrt(80).
__global__ __launch_bounds__(256) void rope_kernel(
    bf16* __restrict__ qp, bf16* __restrict__ kp,
    const float* __restrict__ cosp, const float* __restrict__ sinp)
{
    int idx = blockIdx.x * 256 + threadIdx.x;
    const int NT = M_ * H_ * 5;   // 327680
    bf16* base; float mul;
    if (idx < NT) { base = qp; mul = 0.11180339887498949f; }
    else         { base = kp; mul = 1.0f; idx -= NT; }
    const int row = idx / 80;
    const int rem = idx - row * 80;
    const int h   = rem / 5;
    const int pc  = rem - h * 5;
    const int s   = row & (S_ - 1);
    bf16* p = base + (size_t)row * E_ + h * D_ + pc * 8;
    const float* cp = cosp + s * D_ + pc * 8;
    const float* sp = sinp + s * D_ + pc * 8;
    uint4 olo, ohi;
    rope8(p, p + 40, cp, sp, mul, &olo, &ohi);
    *(uint4*)p        = olo;
    *(uint4*)(p + 40) = ohi;
}

// ============================================================================
// MFMA flash attention v11c — r5's measured-best v11 structure (512 thr,
// 8 waves x 16 q-rows, grid 512, 2 blocks/CU = 16 waves/CU) + two verified
// tweaks:
//  - PT row stride 64 -> 72 elems (144 B = 36 banks): removes the 8-way
//    bank conflict on P-frag b128 reads (identified r7, fix verified v13).
//  - T13 defer-max (THR=8): skip o_acc rescale (20 VALU + exp per tile)
//    when __all(sloc <= m + 8); wave-uniform branch; P bounded by e^8
//    (guide: +5% attn, refcheck'd, data-independent).
// LDS: 20480 (K dbuf) + 20480 (V dbuf) + 8*2304 (PT) = 59392 B.
// ============================================================================
__global__ __launch_bounds__(512, 4) void attn_mfma(
    const bf16* __restrict__ q, const bf16* __restrict__ k, const bf16* __restrict__ vt,
    const int* __restrict__ cu, bf16* __restrict__ o)
{
    __shared__ __align__(16) bf16 Ks[2][64*80];    // 2 x 10240 B, swizzled
    __shared__ __align__(16) bf16 VTs[2][80*64];   // 2 x 10240 B, swizzled
    __shared__ __align__(16) bf16 PTq[8][16*72];   // per-wave P [query][key]

    const int n  = blockIdx.x;                 // 512 blocks
    const int g  = ((n >> 6) << 3) | (n & 7);  // (b,h): XCD = n&7 = h&7
    const int qs = (n >> 3) & 7;               // q-supertile 0..7 (128 rows)
    const int b  = g >> 4;
    const int h  = g & 15;

    const int tid  = threadIdx.x;
    const int lane = tid & 63, wv = tid >> 6;  // wv 0..7
    const int quad = lane >> 4, l15 = lane & 15;
    const int q0   = qs * 128;
    const int len  = cu[b + 1] - cu[b];

    const bool uniformq = (q0 >= len);
    const bool fast     = !uniformq && ((q0 + 128) <= len) && ((len & 63) == 0);
    const int  ktiles   = uniformq ? 16 : (fast ? (len >> 6) : 16);
    const bool domask   = !uniformq && !fast;

    bf16* PT = &PTq[wv][0];

    // Q fragments (B-operand), rows q0 + wv*16 + l15.
    bf16x8 qf[3] = {};
    if (!uniformq) {
        const bf16* qrow = q + (size_t)(b*S_ + q0 + wv*16 + l15)*E_ + h*D_ + quad*8;
        qf[0] = *(const bf16x8*)(qrow);
        qf[1] = *(const bf16x8*)(qrow + 32);
        if (quad < 2) qf[2] = *(const bf16x8*)(qrow + 64);
    }

    float m_s = -1e30f, l_s = 0.f;   // per-lane scalars (query = l15)
    f32x4 o_acc[5] = {};

    bf16x8 pone;
    {
        const short one_s = (short)0x3F80;   // bf16 1.0
        #pragma unroll
        for (int i = 0; i < 8; i++) pone[i] = one_s;
    }

    const int u_  = l15 >> 2;
    const int s0r = quad ^ u_;            // K granule ks=0
    const int sv0 = quad ^ (l15 & 7);     // V granule ks=0

    auto stage = [&](int kt, int bf) {
        #pragma unroll
        for (int i = 0; i < 3; i++) {
            int c = tid + i * 512;
            if (c < 640) {
                if (!uniformq) {
                    int row = c / 10, s5 = c - row * 10;
                    int uu = (row >> 2) & 3;
                    int sg = (s5 < 8) ? (s5 ^ uu) : (8 + ((s5 ^ uu) & 1));
                    gload_lds16(k + (size_t)(b*S_ + kt*64 + row)*E_ + h*D_ + sg*8,
                                &Ks[bf][c*8]);
                }
            } else if (c < 1280) {
                int c2 = c - 640;
                int row = c2 >> 3, s5 = c2 & 7;
                int sg = s5 ^ (row & 7);
                gload_lds16(vt + ((size_t)(b*H_ + h)*D_ + row)*S_ + kt*64 + sg*8,
                            &VTs[bf][c2*8]);
            }
        }
    };

    stage(0, 0);
    __syncthreads();   // buf0 ready

    const bool q_full = (q0 + 128) <= len;   // masked-fallback helper (unused in fast path)
    (void)q_full;

    for (int kt = 0; kt < ktiles; kt++) {
        const int cur = kt & 1;
        if (kt + 1 < ktiles) stage(kt + 1, cur ^ 1);   // loads fly during compute

        bf16x8 pf0 = pone, pf1 = pone;
        if (!uniformq) {
            // ---- QK^T swapped: A=K, B=Q -> C[key=quad*4+r (+nt*16)][query=l15]
            f32x4 s4[4];
            #pragma unroll
            for (int nt = 0; nt < 4; nt++) {
                const bf16* kr = &Ks[cur][(nt*16 + l15) * 80];
                bf16x8 kf0 = *(const bf16x8*)(kr + s0r*8);
                bf16x8 kf1 = *(const bf16x8*)(kr + 32 + s0r*8);
                bf16x8 kf2 = {};
                if (quad < 2) kf2 = *(const bf16x8*)(kr + 64 + (s0r & 1)*8);
                f32x4 a0 = {};
                a0 = __builtin_amdgcn_mfma_f32_16x16x32_bf16(kf0, qf[0], a0, 0, 0, 0);
                a0 = __builtin_amdgcn_mfma_f32_16x16x32_bf16(kf1, qf[1], a0, 0, 0, 0);
                a0 = __builtin_amdgcn_mfma_f32_16x16x32_bf16(kf2, qf[2], a0, 0, 0, 0);
                s4[nt] = a0;
            }

            // ---- masking (lane owns query l15; keys nt*16+quad*4+r)
            float sv[4][4];
            if (!domask) {
                #pragma unroll
                for (int nt = 0; nt < 4; nt++)
                    #pragma unroll
                    for (int r = 0; r < 4; r++)
                        sv[nt][r] = s4[nt][r];
            } else {
                const bool vq = (q0 + wv*16 + l15) < len;
                #pragma unroll
                for (int nt = 0; nt < 4; nt++)
                    #pragma unroll
                    for (int r = 0; r < 4; r++) {
                        const bool vk = (kt*64 + nt*16 + quad*4 + r) < len;
                        sv[nt][r] = (vq && vk) ? s4[nt][r] : -1e9f;
                    }
            }

            // ---- online softmax with T13 defer-max (THR=8)
            float rm[4];
            #pragma unroll
            for (int nt = 0; nt < 4; nt++)
                rm[nt] = fmaxf(fmaxf(sv[nt][0], sv[nt][1]), fmaxf(sv[nt][2], sv[nt][3]));
            float sloc = fmaxf(fmaxf(rm[0], rm[1]), fmaxf(rm[2], rm[3]));
            sloc = fmaxf(sloc, __shfl_xor(sloc, 16, 64));
            sloc = fmaxf(sloc, __shfl_xor(sloc, 32, 64));
            const bool resc = !__all(sloc <= m_s + 8.0f);   // wave-uniform
            const float mnew = resc ? fmaxf(m_s, sloc) : m_s;
            float p[4][4], lsum = 0.f;
            #pragma unroll
            for (int nt = 0; nt < 4; nt++)
                #pragma unroll
                for (int r = 0; r < 4; r++) {
                    p[nt][r] = __expf(sv[nt][r] - mnew);
                    lsum += p[nt][r];
                }
            lsum += __shfl_xor(lsum, 16, 64);
            lsum += __shfl_xor(lsum, 32, 64);
            if (resc) {
                const float alpha = __expf(m_s - mnew);
                l_s = l_s * alpha + lsum;
                m_s = mnew;
                #pragma unroll
                for (int dt = 0; dt < 5; dt++)
                    #pragma unroll
                    for (int r = 0; r < 4; r++)
                        o_acc[dt][r] *= alpha;
            } else {
                l_s += lsum;
            }

            // ---- P -> PT[query][key] (granule-swizzled, stride 72)
            #pragma unroll
            for (int nt = 0; nt < 4; nt++) {
                union { bf16 hh[4]; uint2 u; } w;
                #pragma unroll
                for (int r = 0; r < 4; r++) w.hh[r] = f2b(p[nt][r]);
                const int gw = (2*nt + (quad >> 1)) ^ (l15 & 7);
                *(uint2*)&PT[l15*72 + gw*8 + (quad & 1)*4] = w.u;
            }
            // ---- P-frags (same-wave RAW via lgkmcnt)
            pf0 = *(const bf16x8*)&PT[l15*72 + ((quad    ) ^ (l15 & 7))*8];
            pf1 = *(const bf16x8*)&PT[l15*72 + ((quad + 4) ^ (l15 & 7))*8];
        }

        // ---- PV: A=Vfrag, B=Pfrag -> O[d=quad*4+r (+dt*16)][query=l15]
        #pragma unroll
        for (int dt = 0; dt < 5; dt++) {
            const bf16* vr = &VTs[cur][(dt*16 + l15) * 64];
            bf16x8 vf0 = *(const bf16x8*)(vr + sv0*8);
            bf16x8 vf1 = *(const bf16x8*)(vr + (sv0 ^ 4)*8);
            o_acc[dt] = __builtin_amdgcn_mfma_f32_16x16x32_bf16(vf0, pf0, o_acc[dt], 0, 0, 0);
            o_acc[dt] = __builtin_amdgcn_mfma_f32_16x16x32_bf16(vf1, pf1, o_acc[dt], 0, 0, 0);
        }
        __syncthreads();   // reads of buf[cur] done; buf[cur^1] loads drained
    }

    // ---- epilogue: lane = query l15; d = dt*16 + quad*4 + r
    const float inv = uniformq ? (1.0f / 1024.0f) : (1.0f / l_s);
    const size_t row_g = (size_t)(b*S_ + q0 + wv*16 + l15);
    #pragma unroll
    for (int dt = 0; dt < 5; dt++) {
        union { bf16 hh[4]; uint2 u; } t4;
        #pragma unroll
        for (int r = 0; r < 4; r++) t4.hh[r] = f2b(o_acc[dt][r] * inv);
        *(uint2*)&o[row_g*E_ + h*D_ + dt*16 + quad*4] = t4.u;
    }
}

extern "C" void kernel_launch(void* const* d_in, const int* in_sizes, int n_in,
                              void* d_out, int out_size, void* d_ws, size_t ws_size,
                              hipStream_t stream)
{
    const float* x    = (const float*)d_in[0];
    const int*   cu   = (const int*)  d_in[1];
    const float* cosp = (const float*)d_in[2];
    const float* sinp = (const float*)d_in[3];
    const float* wq   = (const float*)d_in[4];
    const float* bq   = (const float*)d_in[5];
    const float* wk   = (const float*)d_in[6];
    const float* bk   = (const float*)d_in[7];
    const float* wv   = (const float*)d_in[8];
    const float* bv   = (const float*)d_in[9];
    const float* wo   = (const float*)d_in[10];
    const float* bo   = (const float*)d_in[11];
    float* out = (float*)d_out;

    bf16* q   = (bf16*)d_ws;
    bf16* kk  = q   + (size_t)M_ * E_;
    bf16* vt  = kk  + (size_t)M_ * E_;   // transposed V: [B][H][D][S]
    bf16* ao  = vt  + (size_t)M_ * E_;
    bf16* xb  = ao  + (size_t)M_ * E_;
    bf16* wqb = xb  + (size_t)M_ * E_;
    bf16* wkb = wqb + (size_t)E_ * E_;
    bf16* wvb = wkb + (size_t)E_ * E_;
    bf16* wob = wvb + (size_t)E_ * E_;

    // 0) convert x + 4 weight matrices to bf16
    cvt_kernel<<<dim3(2560, 5), 256, 0, stream>>>(
        x, wq, wk, wv, wo, xb, wqb, wkb, wvb, wob, M_*E_, E_*E_);

    // 1) QKV projection: 256x256 8-phase MFMA GEMM (identity block mapping).
    qkv_gemm_8ph<<<dim3(M_/256, 15), 512, 0, stream>>>(
        xb, wqb, wkb, wvb, bq, bk, bv, q, kk, vt);

    // 1.5) one-shot RoPE on q (pre-scaled) and k, in place
    rope_kernel<<<2560, 256, 0, stream>>>(q, kk, cosp, sinp);

    // 2) MFMA flash attention v11c (r5 structure + PT stride 72 + defer-max)
    attn_mfma<<<512, 512, 0, stream>>>(q, kk, vt, cu, ao);

    // 3) output projection (r5's unswapped m97 GEMM, fp32 out, bias fused)
    oproj_gemm<<<dim3(M_/128, E_/128), 256, 0, stream>>>(ao, wob, bo, out);
}

// Round 10
// 239.604 us; speedup vs baseline: 1.0618x; 1.0033x over previous
//
#include <hip/hip_runtime.h>
#include <hip/hip_bf16.h>

#define B_ 4
#define S_ 1024
#define E_ 1280
#define H_ 16
#define D_ 80
#define M_ (B_*S_)   // 4096

typedef __hip_bfloat16 bf16;
using bf16x8 = __attribute__((ext_vector_type(8))) short;  // 8 bf16 = 4 VGPRs
using f32x4  = __attribute__((ext_vector_type(4))) float;  // MFMA C/D frag

__device__ __forceinline__ float b2f(bf16 x){ return __bfloat162float(x); }
__device__ __forceinline__ bf16  f2b(float x){ return __float2bfloat16(x); }

__device__ __forceinline__ void gload_lds16(const void* g, void* l) {
    __builtin_amdgcn_global_load_lds(
        (const __attribute__((address_space(1))) unsigned int*)g,
        (__attribute__((address_space(3))) unsigned int*)l, 16, 0, 0);
}

// 8-phase sync helpers (rule #18: sched_barrier(0) after inline waitcnt)
__device__ __forceinline__ void ph_begin() {
    __builtin_amdgcn_s_barrier();
    asm volatile("s_waitcnt lgkmcnt(0)" ::: "memory");
    __builtin_amdgcn_sched_barrier(0);
    __builtin_amdgcn_s_setprio(1);
}
__device__ __forceinline__ void ph_end() {
    __builtin_amdgcn_s_setprio(0);
    __builtin_amdgcn_sched_barrier(0);
    __builtin_amdgcn_s_barrier();
}
__device__ __forceinline__ void ph_end_vm6() {
    __builtin_amdgcn_s_setprio(0);
    __builtin_amdgcn_sched_barrier(0);
    asm volatile("s_waitcnt vmcnt(6)" ::: "memory");
    __builtin_amdgcn_s_barrier();
}
__device__ __forceinline__ void ph_end_vm0() {
    __builtin_amdgcn_s_setprio(0);
    __builtin_amdgcn_sched_barrier(0);
    asm volatile("s_waitcnt vmcnt(0)" ::: "memory");
    __builtin_amdgcn_s_barrier();
}

// fp32 -> bf16 conversion, 8 elems/thread. blockIdx.y selects segment.
__global__ __launch_bounds__(256) void cvt_kernel(
    const float* __restrict__ s0, const float* __restrict__ s1,
    const float* __restrict__ s2, const float* __restrict__ s3,
    const float* __restrict__ s4,
    bf16* __restrict__ d0, bf16* __restrict__ d1, bf16* __restrict__ d2,
    bf16* __restrict__ d3, bf16* __restrict__ d4,
    int n0, int n1)
{
    const float* s; bf16* d; int n;
    switch (blockIdx.y) {
        case 0: s = s0; d = d0; n = n0; break;
        case 1: s = s1; d = d1; n = n1; break;
        case 2: s = s2; d = d2; n = n1; break;
        case 3: s = s3; d = d3; n = n1; break;
        default: s = s4; d = d4; n = n1; break;
    }
    int i = (blockIdx.x * 256 + threadIdx.x) * 8;
    if (i >= n) return;
    float4 a = *(const float4*)(s + i);
    float4 b = *(const float4*)(s + i + 4);
    bf16 t[8];
    t[0]=f2b(a.x); t[1]=f2b(a.y); t[2]=f2b(a.z); t[3]=f2b(a.w);
    t[4]=f2b(b.x); t[5]=f2b(b.y); t[6]=f2b(b.z); t[7]=f2b(b.w);
    *(uint4*)(d + i) = *(const uint4*)t;
}

// ============================================================================
// QKV projection: 256x256 8-phase MFMA GEMM (T2+T3+T4+T5). Identity block
// mapping. Unchanged (measured 54-55 µs across r8/r9).
// ============================================================================
__global__ __launch_bounds__(512, 2) void qkv_gemm_8ph(
    const bf16* __restrict__ A,
    const bf16* __restrict__ W0, const bf16* __restrict__ W1, const bf16* __restrict__ W2,
    const float* __restrict__ b0, const float* __restrict__ b1, const float* __restrict__ b2,
    bf16* __restrict__ Cq, bf16* __restrict__ Ck, bf16* __restrict__ Cv)
{
    constexpr int K = 1280;
    constexpr int NITER = K / 128;   // 10 iterations, 2 K-tiles each

    __shared__ __align__(16) bf16 Asm[2][2][128*64];   // [buf][half][row*64+col]
    __shared__ __align__(16) bf16 Bsm[2][2][128*64];

    const int bm  = blockIdx.x * 256;
    const int ny  = blockIdx.y;            // 0..14
    const int mat = ny / 5;
    const int bn  = (ny % 5) * 256;        // col base within matrix
    const bf16*  W    = (mat == 0) ? W0 : (mat == 1) ? W1 : W2;
    const float* bias = (mat == 0) ? b0 : (mat == 1) ? b1 : b2;

    const int tid  = threadIdx.x;
    const int lane = tid & 63, wv = tid >> 6;
    const int wm = wv >> 2, wn = wv & 3;        // wave tile: rows wm*128, cols wn*64
    const int quad = lane >> 4, l15 = lane & 15;

    auto stageA = [&](int j_, int half) {
        #pragma unroll
        for (int i = 0; i < 2; i++) {
            const int c   = tid + i*512;
            const int row = c >> 3;
            const int g   = (c & 7) ^ (row & 7);
            gload_lds16(A + (size_t)(bm + half*128 + row) * K + j_*64 + g*8,
                        &Asm[j_ & 1][half][(wv*64 + i*512) * 8]);
        }
    };
    auto stageB = [&](int j_, int half) {
        #pragma unroll
        for (int i = 0; i < 2; i++) {
            const int c   = tid + i*512;
            const int row = c >> 3;
            const int g   = (c & 7) ^ (row & 7);
            gload_lds16(W + (size_t)(bn + half*128 + row) * K + j_*64 + g*8,
                        &Bsm[j_ & 1][half][(wv*64 + i*512) * 8]);
        }
    };
    auto lda = [&](int bf, int mt, int ks) -> bf16x8 {
        const int r = mt*16 + l15;
        return *(const bf16x8*)&Asm[bf][wm][r*64 + (((quad + ks*4) ^ (r & 7)) << 3)];
    };
    auto ldb = [&](int bf, int nt, int ks) -> bf16x8 {
        const int r = (wn & 1)*64 + nt*16 + l15;
        return *(const bf16x8*)&Bsm[bf][wn >> 1][r*64 + (((quad + ks*4) ^ (r & 7)) << 3)];
    };

    f32x4 acc[8][4] = {};
    bf16x8 a[4][2], bA[2][2], bB[2][2];

#define MFMA_Q(MT0, NT0, BB_) do { \
    _Pragma("unroll") for (int mt_ = 0; mt_ < 4; mt_++) \
    _Pragma("unroll") for (int nt_ = 0; nt_ < 2; nt_++) \
    _Pragma("unroll") for (int ks_ = 0; ks_ < 2; ks_++) \
        acc[(MT0)+mt_][(NT0)+nt_] = __builtin_amdgcn_mfma_f32_16x16x32_bf16( \
            a[mt_][ks_], BB_[nt_][ks_], acc[(MT0)+mt_][(NT0)+nt_], 0, 0, 0); \
} while (0)

    stageA(0, 0); stageA(0, 1); stageB(0, 0); stageB(0, 1);
    stageA(1, 0); stageA(1, 1); stageB(1, 0); stageB(1, 1);
    __syncthreads();

    for (int t = 0; t < NITER; t++) {
        const int  j  = 2*t;
        const bool pf = (t + 1 < NITER);

        #pragma unroll
        for (int mt = 0; mt < 4; mt++) { a[mt][0] = lda(0, mt, 0); a[mt][1] = lda(0, mt, 1); }
        #pragma unroll
        for (int nt = 0; nt < 2; nt++) { bA[nt][0] = ldb(0, nt, 0); bA[nt][1] = ldb(0, nt, 1); }
        stageA(j+1, 1);
        ph_begin(); MFMA_Q(0, 0, bA); ph_end();

        #pragma unroll
        for (int nt = 0; nt < 2; nt++) { bB[nt][0] = ldb(0, 2+nt, 0); bB[nt][1] = ldb(0, 2+nt, 1); }
        ph_begin(); MFMA_Q(0, 2, bB); ph_end();

        #pragma unroll
        for (int mt = 0; mt < 4; mt++) { a[mt][0] = lda(0, 4+mt, 0); a[mt][1] = lda(0, 4+mt, 1); }
        if (pf) stageB(j+2, 0);
        ph_begin(); MFMA_Q(4, 0, bA); ph_end();

        if (pf) { stageB(j+2, 1); stageA(j+2, 0); }
        ph_begin(); MFMA_Q(4, 2, bB);
        if (pf) ph_end_vm6(); else ph_end_vm0();

        #pragma unroll
        for (int mt = 0; mt < 4; mt++) { a[mt][0] = lda(1, mt, 0); a[mt][1] = lda(1, mt, 1); }
        #pragma unroll
        for (int nt = 0; nt < 2; nt++) { bA[nt][0] = ldb(1, nt, 0); bA[nt][1] = ldb(1, nt, 1); }
        if (pf) stageA(j+2, 1);
        ph_begin(); MFMA_Q(0, 0, bA); ph_end();

        #pragma unroll
        for (int nt = 0; nt < 2; nt++) { bB[nt][0] = ldb(1, 2+nt, 0); bB[nt][1] = ldb(1, 2+nt, 1); }
        ph_begin(); MFMA_Q(0, 2, bB); ph_end();

        #pragma unroll
        for (int mt = 0; mt < 4; mt++) { a[mt][0] = lda(1, 4+mt, 0); a[mt][1] = lda(1, 4+mt, 1); }
        if (pf) stageB(j+3, 0);
        ph_begin(); MFMA_Q(4, 0, bA); ph_end();

        if (pf) { stageB(j+3, 1); stageA(j+3, 0); }
        ph_begin(); MFMA_Q(4, 2, bB); ph_end_vm6();
    }
#undef MFMA_Q

    if (mat < 2) {
        bf16* C = (mat == 0) ? Cq : Ck;
        #pragma unroll
        for (int nt = 0; nt < 4; nt++) {
            const int ncol = bn + wn*64 + nt*16 + l15;
            const float bv = bias[ncol];
            #pragma unroll
            for (int mt = 0; mt < 8; mt++) {
                const int m0 = bm + wm*128 + mt*16 + quad*4;
                #pragma unroll
                for (int r = 0; r < 4; r++)
                    C[(size_t)(m0 + r) * E_ + ncol] = f2b(acc[mt][nt][r] + bv);
            }
        }
    } else {
        #pragma unroll
        for (int nt = 0; nt < 4; nt++) {
            const int ncol = bn + wn*64 + nt*16 + l15;
            const float bv = bias[ncol];
            const int hh = ncol / 80, dd = ncol % 80;
            #pragma unroll
            for (int mt = 0; mt < 8; mt++) {
                const int m0  = bm + wm*128 + mt*16 + quad*4;
                const int btok = m0 >> 10;
                const int key  = m0 & 1023;
                union { bf16 h[4]; uint2 u; } t4;
                #pragma unroll
                for (int r = 0; r < 4; r++) t4.h[r] = f2b(acc[mt][nt][r] + bv);
                *(uint2*)&Cv[((size_t)(btok*H_ + hh)*D_ + dd)*S_ + key] = t4.u;
            }
        }
    }
}

// ============================================================================
// Output projection: m97-style 128x128 GEMM (unswapped, scalar-store
// epilogue — 32 B contiguous per quarter-wave). Unchanged from r9.
// ============================================================================
__global__ __launch_bounds__(256) void oproj_gemm(
    const bf16* __restrict__ A, const bf16* __restrict__ W,
    const float* __restrict__ bias, float* __restrict__ C)
{
    const int K = E_, N = E_;
    const int bn = blockIdx.y * 128;
    const int bm = blockIdx.x * 128;

    __shared__ bf16 As[2][128][32];
    __shared__ bf16 Ws[2][128][32];

    const int tid  = threadIdx.x;
    const int lane = tid & 63;
    const int wv   = tid >> 6;
    const int wm   = (wv & 1) * 64;
    const int wn   = (wv >> 1) * 64;
    const int srow = wv * 16 + (lane >> 2);
    const int scol = (lane & 3) * 8;

    f32x4 acc[4][4] = {};

    for (int k0 = 0; k0 < K; k0 += 64) {
        __syncthreads();
        #pragma unroll
        for (int p = 0; p < 2; p++) {
            const int kc = k0 + p*32 + scol;
            gload_lds16(A + (size_t)(bm + srow)      * K + kc, &As[p][wv*16][0]);
            gload_lds16(A + (size_t)(bm + 64 + srow) * K + kc, &As[p][64 + wv*16][0]);
            gload_lds16(W + (size_t)(bn + srow)      * K + kc, &Ws[p][wv*16][0]);
            gload_lds16(W + (size_t)(bn + 64 + srow) * K + kc, &Ws[p][64 + wv*16][0]);
        }
        __syncthreads();

        const int fr = lane & 15;
        const int kq = (lane >> 4) * 8;
        #pragma unroll
        for (int p = 0; p < 2; p++) {
            bf16x8 af[4], wf[4];
            #pragma unroll
            for (int t = 0; t < 4; t++) {
                af[t] = *(const bf16x8*)&As[p][wm + t*16 + fr][kq];
                wf[t] = *(const bf16x8*)&Ws[p][wn + t*16 + fr][kq];
            }
            #pragma unroll
            for (int mt = 0; mt < 4; mt++)
                #pragma unroll
                for (int nt = 0; nt < 4; nt++)
                    acc[mt][nt] = __builtin_amdgcn_mfma_f32_16x16x32_bf16(
                        af[mt], wf[nt], acc[mt][nt], 0, 0, 0);
        }
    }

    const int col_l = lane & 15;
    const int row_l = (lane >> 4) * 4;
    #pragma unroll
    for (int nt = 0; nt < 4; nt++) {
        const int n = bn + wn + nt*16 + col_l;
        const float bv = bias[n];
        #pragma unroll
        for (int mt = 0; mt < 4; mt++) {
            #pragma unroll
            for (int r = 0; r < 4; r++) {
                const int m = bm + wm + mt*16 + row_l + r;
                C[(size_t)m * N + n] = acc[mt][nt][r] + bv;
            }
        }
    }
}

// rope helper
__device__ __forceinline__ void rope8(const bf16* lo, const bf16* hi,
                                      const float* cp, const float* sp,
                                      float mul, uint4* out_lo, uint4* out_hi)
{
    union { uint4 u; bf16 h[8]; } li, hi_, lo_o, hi_o;
    li.u  = *(const uint4*)lo;
    hi_.u = *(const uint4*)hi;
    #pragma unroll
    for (int u = 0; u < 8; u++) {
        float x1 = b2f(li.h[u]), x2 = b2f(hi_.h[u]);
        float c = cp[u], s = sp[u];
        lo_o.h[u] = f2b((x1*c - x2*s) * mul);
        hi_o.h[u] = f2b((x2*c + x1*s) * mul);
    }
    *out_lo = lo_o.u;
    *out_hi = hi_o.u;
}

// One-shot in-place RoPE over q and k. Q additionally pre-scaled by 1/sqrt(80).
__global__ __launch_bounds__(256) void rope_kernel(
    bf16* __restrict__ qp, bf16* __restrict__ kp,
    const float* __restrict__ cosp, const float* __restrict__ sinp)
{
    int idx = blockIdx.x * 256 + threadIdx.x;
    const int NT = M_ * H_ * 5;   // 327680
    bf16* base; float mul;
    if (idx < NT) { base = qp; mul = 0.11180339887498949f; }
    else         { base = kp; mul = 1.0f; idx -= NT; }
    const int row = idx / 80;
    const int rem = idx - row * 80;
    const int h   = rem / 5;
    const int pc  = rem - h * 5;
    const int s   = row & (S_ - 1);
    bf16* p = base + (size_t)row * E_ + h * D_ + pc * 8;
    const float* cp = cosp + s * D_ + pc * 8;
    const float* sp = sinp + s * D_ + pc * 8;
    uint4 olo, ohi;
    rope8(p, p + 40, cp, sp, mul, &olo, &ohi);
    *(uint4*)p        = olo;
    *(uint4*)(p + 40) = ohi;
}

// ============================================================================
// MFMA flash attention v11d — v11c with the launch-bounds fix:
// __launch_bounds__(512, 2) instead of (512, 4). Occupancy is LDS-bound
// at 2 blocks/CU (59.4 KB x 2 = 118.8 < 160 KB) = 16 waves/CU, which only
// requires VGPR <= 128. The old (512,4) hard-capped VGPR at 64; v11c's
// added defer-max state spilled at that ceiling (r7 failure mode, milder).
// Spill tell: attn WRITE_SIZE must be exactly 10.24 MB.
// ============================================================================
__global__ __launch_bounds__(512, 2) void attn_mfma(
    const bf16* __restrict__ q, const bf16* __restrict__ k, const bf16* __restrict__ vt,
    const int* __restrict__ cu, bf16* __restrict__ o)
{
    __shared__ __align__(16) bf16 Ks[2][64*80];    // 2 x 10240 B, swizzled
    __shared__ __align__(16) bf16 VTs[2][80*64];   // 2 x 10240 B, swizzled
    __shared__ __align__(16) bf16 PTq[8][16*72];   // per-wave P [query][key]

    const int n  = blockIdx.x;                 // 512 blocks
    const int g  = ((n >> 6) << 3) | (n & 7);  // (b,h): XCD = n&7 = h&7
    const int qs = (n >> 3) & 7;               // q-supertile 0..7 (128 rows)
    const int b  = g >> 4;
    const int h  = g & 15;

    const int tid  = threadIdx.x;
    const int lane = tid & 63, wv = tid >> 6;  // wv 0..7
    const int quad = lane >> 4, l15 = lane & 15;
    const int q0   = qs * 128;
    const int len  = cu[b + 1] - cu[b];

    const bool uniformq = (q0 >= len);
    const bool fast     = !uniformq && ((q0 + 128) <= len) && ((len & 63) == 0);
    const int  ktiles   = uniformq ? 16 : (fast ? (len >> 6) : 16);
    const bool domask   = !uniformq && !fast;

    bf16* PT = &PTq[wv][0];

    // Q fragments (B-operand), rows q0 + wv*16 + l15.
    bf16x8 qf[3] = {};
    if (!uniformq) {
        const bf16* qrow = q + (size_t)(b*S_ + q0 + wv*16 + l15)*E_ + h*D_ + quad*8;
        qf[0] = *(const bf16x8*)(qrow);
        qf[1] = *(const bf16x8*)(qrow + 32);
        if (quad < 2) qf[2] = *(const bf16x8*)(qrow + 64);
    }

    float m_s = -1e30f, l_s = 0.f;   // per-lane scalars (query = l15)
    f32x4 o_acc[5] = {};

    bf16x8 pone;
    {
        const short one_s = (short)0x3F80;   // bf16 1.0
        #pragma unroll
        for (int i = 0; i < 8; i++) pone[i] = one_s;
    }

    const int u_  = l15 >> 2;
    const int s0r = quad ^ u_;            // K granule ks=0
    const int sv0 = quad ^ (l15 & 7);     // V granule ks=0

    auto stage = [&](int kt, int bf) {
        #pragma unroll
        for (int i = 0; i < 3; i++) {
            int c = tid + i * 512;
            if (c < 640) {
                if (!uniformq) {
                    int row = c / 10, s5 = c - row * 10;
                    int uu = (row >> 2) & 3;
                    int sg = (s5 < 8) ? (s5 ^ uu) : (8 + ((s5 ^ uu) & 1));
                    gload_lds16(k + (size_t)(b*S_ + kt*64 + row)*E_ + h*D_ + sg*8,
                                &Ks[bf][c*8]);
                }
            } else if (c < 1280) {
                int c2 = c - 640;
                int row = c2 >> 3, s5 = c2 & 7;
                int sg = s5 ^ (row & 7);
                gload_lds16(vt + ((size_t)(b*H_ + h)*D_ + row)*S_ + kt*64 + sg*8,
                            &VTs[bf][c2*8]);
            }
        }
    };

    stage(0, 0);
    __syncthreads();   // buf0 ready

    for (int kt = 0; kt < ktiles; kt++) {
        const int cur = kt & 1;
        if (kt + 1 < ktiles) stage(kt + 1, cur ^ 1);   // loads fly during compute

        bf16x8 pf0 = pone, pf1 = pone;
        if (!uniformq) {
            // ---- QK^T swapped: A=K, B=Q -> C[key=quad*4+r (+nt*16)][query=l15]
            f32x4 s4[4];
            #pragma unroll
            for (int nt = 0; nt < 4; nt++) {
                const bf16* kr = &Ks[cur][(nt*16 + l15) * 80];
                bf16x8 kf0 = *(const bf16x8*)(kr + s0r*8);
                bf16x8 kf1 = *(const bf16x8*)(kr + 32 + s0r*8);
                bf16x8 kf2 = {};
                if (quad < 2) kf2 = *(const bf16x8*)(kr + 64 + (s0r & 1)*8);
                f32x4 a0 = {};
                a0 = __builtin_amdgcn_mfma_f32_16x16x32_bf16(kf0, qf[0], a0, 0, 0, 0);
                a0 = __builtin_amdgcn_mfma_f32_16x16x32_bf16(kf1, qf[1], a0, 0, 0, 0);
                a0 = __builtin_amdgcn_mfma_f32_16x16x32_bf16(kf2, qf[2], a0, 0, 0, 0);
                s4[nt] = a0;
            }

            // ---- masking (lane owns query l15; keys nt*16+quad*4+r)
            float sv[4][4];
            if (!domask) {
                #pragma unroll
                for (int nt = 0; nt < 4; nt++)
                    #pragma unroll
                    for (int r = 0; r < 4; r++)
                        sv[nt][r] = s4[nt][r];
            } else {
                const bool vq = (q0 + wv*16 + l15) < len;
                #pragma unroll
                for (int nt = 0; nt < 4; nt++)
                    #pragma unroll
                    for (int r = 0; r < 4; r++) {
                        const bool vk = (kt*64 + nt*16 + quad*4 + r) < len;
                        sv[nt][r] = (vq && vk) ? s4[nt][r] : -1e9f;
                    }
            }

            // ---- online softmax with T13 defer-max (THR=8)
            float rm[4];
            #pragma unroll
            for (int nt = 0; nt < 4; nt++)
                rm[nt] = fmaxf(fmaxf(sv[nt][0], sv[nt][1]), fmaxf(sv[nt][2], sv[nt][3]));
            float sloc = fmaxf(fmaxf(rm[0], rm[1]), fmaxf(rm[2], rm[3]));
            sloc = fmaxf(sloc, __shfl_xor(sloc, 16, 64));
            sloc = fmaxf(sloc, __shfl_xor(sloc, 32, 64));
            const bool resc = !__all(sloc <= m_s + 8.0f);   // wave-uniform
            const float mnew = resc ? fmaxf(m_s, sloc) : m_s;
            float p[4][4], lsum = 0.f;
            #pragma unroll
            for (int nt = 0; nt < 4; nt++)
                #pragma unroll
                for (int r = 0; r < 4; r++) {
                    p[nt][r] = __expf(sv[nt][r] - mnew);
                    lsum += p[nt][r];
                }
            lsum += __shfl_xor(lsum, 16, 64);
            lsum += __shfl_xor(lsum, 32, 64);
            if (resc) {
                const float alpha = __expf(m_s - mnew);
                l_s = l_s * alpha + lsum;
                m_s = mnew;
                #pragma unroll
                for (int dt = 0; dt < 5; dt++)
                    #pragma unroll
                    for (int r = 0; r < 4; r++)
                        o_acc[dt][r] *= alpha;
            } else {
                l_s += lsum;
            }

            // ---- P -> PT[query][key] (granule-swizzled, stride 72)
            #pragma unroll
            for (int nt = 0; nt < 4; nt++) {
                union { bf16 hh[4]; uint2 u; } w;
                #pragma unroll
                for (int r = 0; r < 4; r++) w.hh[r] = f2b(p[nt][r]);
                const int gw = (2*nt + (quad >> 1)) ^ (l15 & 7);
                *(uint2*)&PT[l15*72 + gw*8 + (quad & 1)*4] = w.u;
            }
            // ---- P-frags (same-wave RAW via lgkmcnt)
            pf0 = *(const bf16x8*)&PT[l15*72 + ((quad    ) ^ (l15 & 7))*8];
            pf1 = *(const bf16x8*)&PT[l15*72 + ((quad + 4) ^ (l15 & 7))*8];
        }

        // ---- PV: A=Vfrag, B=Pfrag -> O[d=quad*4+r (+dt*16)][query=l15]
        #pragma unroll
        for (int dt = 0; dt < 5; dt++) {
            const bf16* vr = &VTs[cur][(dt*16 + l15) * 64];
            bf16x8 vf0 = *(const bf16x8*)(vr + sv0*8);
            bf16x8 vf1 = *(const bf16x8*)(vr + (sv0 ^ 4)*8);
            o_acc[dt] = __builtin_amdgcn_mfma_f32_16x16x32_bf16(vf0, pf0, o_acc[dt], 0, 0, 0);
            o_acc[dt] = __builtin_amdgcn_mfma_f32_16x16x32_bf16(vf1, pf1, o_acc[dt], 0, 0, 0);
        }
        __syncthreads();   // reads of buf[cur] done; buf[cur^1] loads drained
    }

    // ---- epilogue: lane = query l15; d = dt*16 + quad*4 + r
    const float inv = uniformq ? (1.0f / 1024.0f) : (1.0f / l_s);
    const size_t row_g = (size_t)(b*S_ + q0 + wv*16 + l15);
    #pragma unroll
    for (int dt = 0; dt < 5; dt++) {
        union { bf16 hh[4]; uint2 u; } t4;
        #pragma unroll
        for (int r = 0; r < 4; r++) t4.hh[r] = f2b(o_acc[dt][r] * inv);
        *(uint2*)&o[row_g*E_ + h*D_ + dt*16 + quad*4] = t4.u;
    }
}

extern "C" void kernel_launch(void* const* d_in, const int* in_sizes, int n_in,
                              void* d_out, int out_size, void* d_ws, size_t ws_size,
                              hipStream_t stream)
{
    const float* x    = (const float*)d_in[0];
    const int*   cu   = (const int*)  d_in[1];
    const float* cosp = (const float*)d_in[2];
    const float* sinp = (const float*)d_in[3];
    const float* wq   = (const float*)d_in[4];
    const float* bq   = (const float*)d_in[5];
    const float* wk   = (const float*)d_in[6];
    const float* bk   = (const float*)d_in[7];
    const float* wv   = (const float*)d_in[8];
    const float* bv   = (const float*)d_in[9];
    const float* wo   = (const float*)d_in[10];
    const float* bo   = (const float*)d_in[11];
    float* out = (float*)d_out;

    bf16* q   = (bf16*)d_ws;
    bf16* kk  = q   + (size_t)M_ * E_;
    bf16* vt  = kk  + (size_t)M_ * E_;   // transposed V: [B][H][D][S]
    bf16* ao  = vt  + (size_t)M_ * E_;
    bf16* xb  = ao  + (size_t)M_ * E_;
    bf16* wqb = xb  + (size_t)M_ * E_;
    bf16* wkb = wqb + (size_t)E_ * E_;
    bf16* wvb = wkb + (size_t)E_ * E_;
    bf16* wob = wvb + (size_t)E_ * E_;

    // 0) convert x + 4 weight matrices to bf16
    cvt_kernel<<<dim3(2560, 5), 256, 0, stream>>>(
        x, wq, wk, wv, wo, xb, wqb, wkb, wvb, wob, M_*E_, E_*E_);

    // 1) QKV projection: 256x256 8-phase MFMA GEMM (identity block mapping).
    qkv_gemm_8ph<<<dim3(M_/256, 15), 512, 0, stream>>>(
        xb, wqb, wkb, wvb, bq, bk, bv, q, kk, vt);

    // 1.5) one-shot RoPE on q (pre-scaled) and k, in place
    rope_kernel<<<2560, 256, 0, stream>>>(q, kk, cosp, sinp);

    // 2) MFMA flash attention v11d (launch-bounds fix: (512,2))
    attn_mfma<<<512, 512, 0, stream>>>(q, kk, vt, cu, ao);

    // 3) output projection (m97 GEMM, fp32 out, bias fused)
    oproj_gemm<<<dim3(M_/128, E_/128), 256, 0, stream>>>(ao, wob, bo, out);
}

// Round 11
// 232.568 us; speedup vs baseline: 1.0939x; 1.0303x over previous
//
#include <hip/hip_runtime.h>
#include <hip/hip_bf16.h>

#define B_ 4
#define S_ 1024
#define E_ 1280
#define H_ 16
#define D_ 80
#define M_ (B_*S_)   // 4096

typedef __hip_bfloat16 bf16;
using bf16x8 = __attribute__((ext_vector_type(8))) short;  // 8 bf16 = 4 VGPRs
using f32x4  = __attribute__((ext_vector_type(4))) float;  // MFMA C/D frag

__device__ __forceinline__ float b2f(bf16 x){ return __bfloat162float(x); }
__device__ __forceinline__ bf16  f2b(float x){ return __float2bfloat16(x); }

__device__ __forceinline__ void gload_lds16(const void* g, void* l) {
    __builtin_amdgcn_global_load_lds(
        (const __attribute__((address_space(1))) unsigned int*)g,
        (__attribute__((address_space(3))) unsigned int*)l, 16, 0, 0);
}

// 8-phase sync helpers (rule #18: sched_barrier(0) after inline waitcnt)
__device__ __forceinline__ void ph_begin() {
    __builtin_amdgcn_s_barrier();
    asm volatile("s_waitcnt lgkmcnt(0)" ::: "memory");
    __builtin_amdgcn_sched_barrier(0);
    __builtin_amdgcn_s_setprio(1);
}
__device__ __forceinline__ void ph_end() {
    __builtin_amdgcn_s_setprio(0);
    __builtin_amdgcn_sched_barrier(0);
    __builtin_amdgcn_s_barrier();
}
__device__ __forceinline__ void ph_end_vm6() {
    __builtin_amdgcn_s_setprio(0);
    __builtin_amdgcn_sched_barrier(0);
    asm volatile("s_waitcnt vmcnt(6)" ::: "memory");
    __builtin_amdgcn_s_barrier();
}
__device__ __forceinline__ void ph_end_vm0() {
    __builtin_amdgcn_s_setprio(0);
    __builtin_amdgcn_sched_barrier(0);
    asm volatile("s_waitcnt vmcnt(0)" ::: "memory");
    __builtin_amdgcn_s_barrier();
}

// ============================================================================
// fp32 -> bf16 conversion, 8 elems/thread. blockIdx.y selects segment.
// Segments 1 (wq) and 2 (wk) are written with PAIR-INTERLEAVED rows:
// dest row h*80+2d <- src row h*80+d (d<40), dest row h*80+2d+1 <- h*80+40+d.
// This makes each RoPE pair adjacent in the q/k column space, so rope in the
// qkv epilogue is a lane-pair shfl (no LDS, no extra kernel). Attention is
// invariant to this permutation (QK^T sums over d; PV doesn't touch it).
// ============================================================================
__global__ __launch_bounds__(256) void cvt_kernel(
    const float* __restrict__ s0, const float* __restrict__ s1,
    const float* __restrict__ s2, const float* __restrict__ s3,
    const float* __restrict__ s4,
    bf16* __restrict__ d0, bf16* __restrict__ d1, bf16* __restrict__ d2,
    bf16* __restrict__ d3, bf16* __restrict__ d4,
    int n0, int n1)
{
    const float* s; bf16* d; int n;
    bool perm = false;
    switch (blockIdx.y) {
        case 0: s = s0; d = d0; n = n0; break;
        case 1: s = s1; d = d1; n = n1; perm = true; break;
        case 2: s = s2; d = d2; n = n1; perm = true; break;
        case 3: s = s3; d = d3; n = n1; break;
        default: s = s4; d = d4; n = n1; break;
    }
    int i = (blockIdx.x * 256 + threadIdx.x) * 8;
    if (i >= n) return;
    const float* src = s + i;
    if (perm) {
        const int row = i / E_;           // dest row (permuted position)
        const int col = i - row * E_;
        const int e   = row % 80;
        const int nr  = (row - e) + ((e & 1) ? 40 + (e >> 1) : (e >> 1));
        src = s + (size_t)nr * E_ + col;
    }
    float4 a = *(const float4*)(src);
    float4 b = *(const float4*)(src + 4);
    bf16 t[8];
    t[0]=f2b(a.x); t[1]=f2b(a.y); t[2]=f2b(a.z); t[3]=f2b(a.w);
    t[4]=f2b(b.x); t[5]=f2b(b.y); t[6]=f2b(b.z); t[7]=f2b(b.w);
    *(uint4*)(d + i) = *(const uint4*)t;
}

// ============================================================================
// QKV projection: 256x256 8-phase MFMA GEMM (T2+T3+T4+T5), identity block
// mapping, + FUSED ROPE in the epilogue for mats 0,1 (q,k):
//  - wq/wk rows pre-permuted pair-interleaved (see cvt) -> the rope partner
//    of column p is p^1 -> pv = __shfl_xor(v,1) (DPP, no LDS).
//  - cos idx = (p%80)>>1 for both halves (cos[s,40+j]==cos[s,j] exactly).
//  - even p: v*c - pv*s ; odd p: v*c + pv*s ; Q additionally scaled 1/sqrt(80).
//  - bias fetched through the inverse permutation.
// mat 2 (V): unchanged transposed-VT epilogue, bias[ncol] direct.
// This removes the standalone rope_kernel (one fewer launch).
// ============================================================================
__global__ __launch_bounds__(512, 2) void qkv_gemm_8ph(
    const bf16* __restrict__ A,
    const bf16* __restrict__ W0, const bf16* __restrict__ W1, const bf16* __restrict__ W2,
    const float* __restrict__ b0, const float* __restrict__ b1, const float* __restrict__ b2,
    const float* __restrict__ cosp, const float* __restrict__ sinp,
    bf16* __restrict__ Cq, bf16* __restrict__ Ck, bf16* __restrict__ Cv)
{
    constexpr int K = 1280;
    constexpr int NITER = K / 128;   // 10 iterations, 2 K-tiles each

    __shared__ __align__(16) bf16 Asm[2][2][128*64];   // [buf][half][row*64+col]
    __shared__ __align__(16) bf16 Bsm[2][2][128*64];

    const int bm  = blockIdx.x * 256;
    const int ny  = blockIdx.y;            // 0..14
    const int mat = ny / 5;
    const int bn  = (ny % 5) * 256;        // col base within matrix
    const bf16*  W    = (mat == 0) ? W0 : (mat == 1) ? W1 : W2;
    const float* bias = (mat == 0) ? b0 : (mat == 1) ? b1 : b2;

    const int tid  = threadIdx.x;
    const int lane = tid & 63, wv = tid >> 6;
    const int wm = wv >> 2, wn = wv & 3;        // wave tile: rows wm*128, cols wn*64
    const int quad = lane >> 4, l15 = lane & 15;

    auto stageA = [&](int j_, int half) {
        #pragma unroll
        for (int i = 0; i < 2; i++) {
            const int c   = tid + i*512;
            const int row = c >> 3;
            const int g   = (c & 7) ^ (row & 7);
            gload_lds16(A + (size_t)(bm + half*128 + row) * K + j_*64 + g*8,
                        &Asm[j_ & 1][half][(wv*64 + i*512) * 8]);
        }
    };
    auto stageB = [&](int j_, int half) {
        #pragma unroll
        for (int i = 0; i < 2; i++) {
            const int c   = tid + i*512;
            const int row = c >> 3;
            const int g   = (c & 7) ^ (row & 7);
            gload_lds16(W + (size_t)(bn + half*128 + row) * K + j_*64 + g*8,
                        &Bsm[j_ & 1][half][(wv*64 + i*512) * 8]);
        }
    };
    auto lda = [&](int bf, int mt, int ks) -> bf16x8 {
        const int r = mt*16 + l15;
        return *(const bf16x8*)&Asm[bf][wm][r*64 + (((quad + ks*4) ^ (r & 7)) << 3)];
    };
    auto ldb = [&](int bf, int nt, int ks) -> bf16x8 {
        const int r = (wn & 1)*64 + nt*16 + l15;
        return *(const bf16x8*)&Bsm[bf][wn >> 1][r*64 + (((quad + ks*4) ^ (r & 7)) << 3)];
    };

    f32x4 acc[8][4] = {};
    bf16x8 a[4][2], bA[2][2], bB[2][2];

#define MFMA_Q(MT0, NT0, BB_) do { \
    _Pragma("unroll") for (int mt_ = 0; mt_ < 4; mt_++) \
    _Pragma("unroll") for (int nt_ = 0; nt_ < 2; nt_++) \
    _Pragma("unroll") for (int ks_ = 0; ks_ < 2; ks_++) \
        acc[(MT0)+mt_][(NT0)+nt_] = __builtin_amdgcn_mfma_f32_16x16x32_bf16( \
            a[mt_][ks_], BB_[nt_][ks_], acc[(MT0)+mt_][(NT0)+nt_], 0, 0, 0); \
} while (0)

    stageA(0, 0); stageA(0, 1); stageB(0, 0); stageB(0, 1);
    stageA(1, 0); stageA(1, 1); stageB(1, 0); stageB(1, 1);
    __syncthreads();

    for (int t = 0; t < NITER; t++) {
        const int  j  = 2*t;
        const bool pf = (t + 1 < NITER);

        #pragma unroll
        for (int mt = 0; mt < 4; mt++) { a[mt][0] = lda(0, mt, 0); a[mt][1] = lda(0, mt, 1); }
        #pragma unroll
        for (int nt = 0; nt < 2; nt++) { bA[nt][0] = ldb(0, nt, 0); bA[nt][1] = ldb(0, nt, 1); }
        stageA(j+1, 1);
        ph_begin(); MFMA_Q(0, 0, bA); ph_end();

        #pragma unroll
        for (int nt = 0; nt < 2; nt++) { bB[nt][0] = ldb(0, 2+nt, 0); bB[nt][1] = ldb(0, 2+nt, 1); }
        ph_begin(); MFMA_Q(0, 2, bB); ph_end();

        #pragma unroll
        for (int mt = 0; mt < 4; mt++) { a[mt][0] = lda(0, 4+mt, 0); a[mt][1] = lda(0, 4+mt, 1); }
        if (pf) stageB(j+2, 0);
        ph_begin(); MFMA_Q(4, 0, bA); ph_end();

        if (pf) { stageB(j+2, 1); stageA(j+2, 0); }
        ph_begin(); MFMA_Q(4, 2, bB);
        if (pf) ph_end_vm6(); else ph_end_vm0();

        #pragma unroll
        for (int mt = 0; mt < 4; mt++) { a[mt][0] = lda(1, mt, 0); a[mt][1] = lda(1, mt, 1); }
        #pragma unroll
        for (int nt = 0; nt < 2; nt++) { bA[nt][0] = ldb(1, nt, 0); bA[nt][1] = ldb(1, nt, 1); }
        if (pf) stageA(j+2, 1);
        ph_begin(); MFMA_Q(0, 0, bA); ph_end();

        #pragma unroll
        for (int nt = 0; nt < 2; nt++) { bB[nt][0] = ldb(1, 2+nt, 0); bB[nt][1] = ldb(1, 2+nt, 1); }
        ph_begin(); MFMA_Q(0, 2, bB); ph_end();

        #pragma unroll
        for (int mt = 0; mt < 4; mt++) { a[mt][0] = lda(1, 4+mt, 0); a[mt][1] = lda(1, 4+mt, 1); }
        if (pf) stageB(j+3, 0);
        ph_begin(); MFMA_Q(4, 0, bA); ph_end();

        if (pf) { stageB(j+3, 1); stageA(j+3, 0); }
        ph_begin(); MFMA_Q(4, 2, bB); ph_end_vm6();
    }
#undef MFMA_Q

    if (mat < 2) {
        bf16* C = (mat == 0) ? Cq : Ck;
        const float mul = (mat == 0) ? 0.11180339887498949f : 1.0f;
        #pragma unroll
        for (int nt = 0; nt < 4; nt++) {
            const int p  = bn + wn*64 + nt*16 + l15;   // permuted output col
            const int e  = p % 80;
            const int nr = (p - e) + ((e & 1) ? 40 + (e >> 1) : (e >> 1));
            const float bv = bias[nr];                 // bias via inverse perm
            const int dcs  = e >> 1;                   // cos/sin index (0..39)
            const bool odd = (e & 1);
            #pragma unroll
            for (int mt = 0; mt < 8; mt++) {
                const int m0 = bm + wm*128 + mt*16 + quad*4;
                #pragma unroll
                for (int r = 0; r < 4; r++) {
                    const int m = m0 + r;
                    const int s = m & (S_ - 1);
                    const float c  = cosp[s*D_ + dcs];
                    const float sn = sinp[s*D_ + dcs];
                    const float v  = acc[mt][nt][r] + bv;
                    const float pv = __shfl_xor(v, 1, 64);   // rope partner
                    const float out = odd ? (v*c + pv*sn) : (v*c - pv*sn);
                    C[(size_t)m * E_ + p] = f2b(out * mul);
                }
            }
        }
    } else {
        #pragma unroll
        for (int nt = 0; nt < 4; nt++) {
            const int ncol = bn + wn*64 + nt*16 + l15;
            const float bv = bias[ncol];
            const int hh = ncol / 80, dd = ncol % 80;
            #pragma unroll
            for (int mt = 0; mt < 8; mt++) {
                const int m0  = bm + wm*128 + mt*16 + quad*4;
                const int btok = m0 >> 10;
                const int key  = m0 & 1023;
                union { bf16 h[4]; uint2 u; } t4;
                #pragma unroll
                for (int r = 0; r < 4; r++) t4.h[r] = f2b(acc[mt][nt][r] + bv);
                *(uint2*)&Cv[((size_t)(btok*H_ + hh)*D_ + dd)*S_ + key] = t4.u;
            }
        }
    }
}

// ============================================================================
// Output projection: m97-style 128x128 GEMM (unswapped, scalar-store
// epilogue — 32 B contiguous per quarter-wave). Unchanged from r10.
// ============================================================================
__global__ __launch_bounds__(256) void oproj_gemm(
    const bf16* __restrict__ A, const bf16* __restrict__ W,
    const float* __restrict__ bias, float* __restrict__ C)
{
    const int K = E_, N = E_;
    const int bn = blockIdx.y * 128;
    const int bm = blockIdx.x * 128;

    __shared__ bf16 As[2][128][32];
    __shared__ bf16 Ws[2][128][32];

    const int tid  = threadIdx.x;
    const int lane = tid & 63;
    const int wv   = tid >> 6;
    const int wm   = (wv & 1) * 64;
    const int wn   = (wv >> 1) * 64;
    const int srow = wv * 16 + (lane >> 2);
    const int scol = (lane & 3) * 8;

    f32x4 acc[4][4] = {};

    for (int k0 = 0; k0 < K; k0 += 64) {
        __syncthreads();
        #pragma unroll
        for (int p = 0; p < 2; p++) {
            const int kc = k0 + p*32 + scol;
            gload_lds16(A + (size_t)(bm + srow)      * K + kc, &As[p][wv*16][0]);
            gload_lds16(A + (size_t)(bm + 64 + srow) * K + kc, &As[p][64 + wv*16][0]);
            gload_lds16(W + (size_t)(bn + srow)      * K + kc, &Ws[p][wv*16][0]);
            gload_lds16(W + (size_t)(bn + 64 + srow) * K + kc, &Ws[p][64 + wv*16][0]);
        }
        __syncthreads();

        const int fr = lane & 15;
        const int kq = (lane >> 4) * 8;
        #pragma unroll
        for (int p = 0; p < 2; p++) {
            bf16x8 af[4], wf[4];
            #pragma unroll
            for (int t = 0; t < 4; t++) {
                af[t] = *(const bf16x8*)&As[p][wm + t*16 + fr][kq];
                wf[t] = *(const bf16x8*)&Ws[p][wn + t*16 + fr][kq];
            }
            #pragma unroll
            for (int mt = 0; mt < 4; mt++)
                #pragma unroll
                for (int nt = 0; nt < 4; nt++)
                    acc[mt][nt] = __builtin_amdgcn_mfma_f32_16x16x32_bf16(
                        af[mt], wf[nt], acc[mt][nt], 0, 0, 0);
        }
    }

    const int col_l = lane & 15;
    const int row_l = (lane >> 4) * 4;
    #pragma unroll
    for (int nt = 0; nt < 4; nt++) {
        const int n = bn + wn + nt*16 + col_l;
        const float bv = bias[n];
        #pragma unroll
        for (int mt = 0; mt < 4; mt++) {
            #pragma unroll
            for (int r = 0; r < 4; r++) {
                const int m = bm + wm + mt*16 + row_l + r;
                C[(size_t)m * N + n] = acc[mt][nt][r] + bv;
            }
        }
    }
}

// ============================================================================
// MFMA flash attention v11d — unchanged from r10. q/k arrive pre-roped,
// pre-scaled, in pair-interleaved D layout (QK^T is invariant to any fixed
// permutation of D applied to both q and k; PV/output don't touch it).
// ============================================================================
__global__ __launch_bounds__(512, 2) void attn_mfma(
    const bf16* __restrict__ q, const bf16* __restrict__ k, const bf16* __restrict__ vt,
    const int* __restrict__ cu, bf16* __restrict__ o)
{
    __shared__ __align__(16) bf16 Ks[2][64*80];    // 2 x 10240 B, swizzled
    __shared__ __align__(16) bf16 VTs[2][80*64];   // 2 x 10240 B, swizzled
    __shared__ __align__(16) bf16 PTq[8][16*72];   // per-wave P [query][key]

    const int n  = blockIdx.x;                 // 512 blocks
    const int g  = ((n >> 6) << 3) | (n & 7);  // (b,h): XCD = n&7 = h&7
    const int qs = (n >> 3) & 7;               // q-supertile 0..7 (128 rows)
    const int b  = g >> 4;
    const int h  = g & 15;

    const int tid  = threadIdx.x;
    const int lane = tid & 63, wv = tid >> 6;  // wv 0..7
    const int quad = lane >> 4, l15 = lane & 15;
    const int q0   = qs * 128;
    const int len  = cu[b + 1] - cu[b];

    const bool uniformq = (q0 >= len);
    const bool fast     = !uniformq && ((q0 + 128) <= len) && ((len & 63) == 0);
    const int  ktiles   = uniformq ? 16 : (fast ? (len >> 6) : 16);
    const bool domask   = !uniformq && !fast;

    bf16* PT = &PTq[wv][0];

    // Q fragments (B-operand), rows q0 + wv*16 + l15.
    bf16x8 qf[3] = {};
    if (!uniformq) {
        const bf16* qrow = q + (size_t)(b*S_ + q0 + wv*16 + l15)*E_ + h*D_ + quad*8;
        qf[0] = *(const bf16x8*)(qrow);
        qf[1] = *(const bf16x8*)(qrow + 32);
        if (quad < 2) qf[2] = *(const bf16x8*)(qrow + 64);
    }

    float m_s = -1e30f, l_s = 0.f;   // per-lane scalars (query = l15)
    f32x4 o_acc[5] = {};

    bf16x8 pone;
    {
        const short one_s = (short)0x3F80;   // bf16 1.0
        #pragma unroll
        for (int i = 0; i < 8; i++) pone[i] = one_s;
    }

    const int u_  = l15 >> 2;
    const int s0r = quad ^ u_;            // K granule ks=0
    const int sv0 = quad ^ (l15 & 7);     // V granule ks=0

    auto stage = [&](int kt, int bf) {
        #pragma unroll
        for (int i = 0; i < 3; i++) {
            int c = tid + i * 512;
            if (c < 640) {
                if (!uniformq) {
                    int row = c / 10, s5 = c - row * 10;
                    int uu = (row >> 2) & 3;
                    int sg = (s5 < 8) ? (s5 ^ uu) : (8 + ((s5 ^ uu) & 1));
                    gload_lds16(k + (size_t)(b*S_ + kt*64 + row)*E_ + h*D_ + sg*8,
                                &Ks[bf][c*8]);
                }
            } else if (c < 1280) {
                int c2 = c - 640;
                int row = c2 >> 3, s5 = c2 & 7;
                int sg = s5 ^ (row & 7);
                gload_lds16(vt + ((size_t)(b*H_ + h)*D_ + row)*S_ + kt*64 + sg*8,
                            &VTs[bf][c2*8]);
            }
        }
    };

    stage(0, 0);
    __syncthreads();   // buf0 ready

    for (int kt = 0; kt < ktiles; kt++) {
        const int cur = kt & 1;
        if (kt + 1 < ktiles) stage(kt + 1, cur ^ 1);   // loads fly during compute

        bf16x8 pf0 = pone, pf1 = pone;
        if (!uniformq) {
            // ---- QK^T swapped: A=K, B=Q -> C[key=quad*4+r (+nt*16)][query=l15]
            f32x4 s4[4];
            #pragma unroll
            for (int nt = 0; nt < 4; nt++) {
                const bf16* kr = &Ks[cur][(nt*16 + l15) * 80];
                bf16x8 kf0 = *(const bf16x8*)(kr + s0r*8);
                bf16x8 kf1 = *(const bf16x8*)(kr + 32 + s0r*8);
                bf16x8 kf2 = {};
                if (quad < 2) kf2 = *(const bf16x8*)(kr + 64 + (s0r & 1)*8);
                f32x4 a0 = {};
                a0 = __builtin_amdgcn_mfma_f32_16x16x32_bf16(kf0, qf[0], a0, 0, 0, 0);
                a0 = __builtin_amdgcn_mfma_f32_16x16x32_bf16(kf1, qf[1], a0, 0, 0, 0);
                a0 = __builtin_amdgcn_mfma_f32_16x16x32_bf16(kf2, qf[2], a0, 0, 0, 0);
                s4[nt] = a0;
            }

            // ---- masking (lane owns query l15; keys nt*16+quad*4+r)
            float sv[4][4];
            if (!domask) {
                #pragma unroll
                for (int nt = 0; nt < 4; nt++)
                    #pragma unroll
                    for (int r = 0; r < 4; r++)
                        sv[nt][r] = s4[nt][r];
            } else {
                const bool vq = (q0 + wv*16 + l15) < len;
                #pragma unroll
                for (int nt = 0; nt < 4; nt++)
                    #pragma unroll
                    for (int r = 0; r < 4; r++) {
                        const bool vk = (kt*64 + nt*16 + quad*4 + r) < len;
                        sv[nt][r] = (vq && vk) ? s4[nt][r] : -1e9f;
                    }
            }

            // ---- online softmax with T13 defer-max (THR=8)
            float rm[4];
            #pragma unroll
            for (int nt = 0; nt < 4; nt++)
                rm[nt] = fmaxf(fmaxf(sv[nt][0], sv[nt][1]), fmaxf(sv[nt][2], sv[nt][3]));
            float sloc = fmaxf(fmaxf(rm[0], rm[1]), fmaxf(rm[2], rm[3]));
            sloc = fmaxf(sloc, __shfl_xor(sloc, 16, 64));
            sloc = fmaxf(sloc, __shfl_xor(sloc, 32, 64));
            const bool resc = !__all(sloc <= m_s + 8.0f);   // wave-uniform
            const float mnew = resc ? fmaxf(m_s, sloc) : m_s;
            float p[4][4], lsum = 0.f;
            #pragma unroll
            for (int nt = 0; nt < 4; nt++)
                #pragma unroll
                for (int r = 0; r < 4; r++) {
                    p[nt][r] = __expf(sv[nt][r] - mnew);
                    lsum += p[nt][r];
                }
            lsum += __shfl_xor(lsum, 16, 64);
            lsum += __shfl_xor(lsum, 32, 64);
            if (resc) {
                const float alpha = __expf(m_s - mnew);
                l_s = l_s * alpha + lsum;
                m_s = mnew;
                #pragma unroll
                for (int dt = 0; dt < 5; dt++)
                    #pragma unroll
                    for (int r = 0; r < 4; r++)
                        o_acc[dt][r] *= alpha;
            } else {
                l_s += lsum;
            }

            // ---- P -> PT[query][key] (granule-swizzled, stride 72)
            #pragma unroll
            for (int nt = 0; nt < 4; nt++) {
                union { bf16 hh[4]; uint2 u; } w;
                #pragma unroll
                for (int r = 0; r < 4; r++) w.hh[r] = f2b(p[nt][r]);
                const int gw = (2*nt + (quad >> 1)) ^ (l15 & 7);
                *(uint2*)&PT[l15*72 + gw*8 + (quad & 1)*4] = w.u;
            }
            // ---- P-frags (same-wave RAW via lgkmcnt)
            pf0 = *(const bf16x8*)&PT[l15*72 + ((quad    ) ^ (l15 & 7))*8];
            pf1 = *(const bf16x8*)&PT[l15*72 + ((quad + 4) ^ (l15 & 7))*8];
        }

        // ---- PV: A=Vfrag, B=Pfrag -> O[d=quad*4+r (+dt*16)][query=l15]
        #pragma unroll
        for (int dt = 0; dt < 5; dt++) {
            const bf16* vr = &VTs[cur][(dt*16 + l15) * 64];
            bf16x8 vf0 = *(const bf16x8*)(vr + sv0*8);
            bf16x8 vf1 = *(const bf16x8*)(vr + (sv0 ^ 4)*8);
            o_acc[dt] = __builtin_amdgcn_mfma_f32_16x16x32_bf16(vf0, pf0, o_acc[dt], 0, 0, 0);
            o_acc[dt] = __builtin_amdgcn_mfma_f32_16x16x32_bf16(vf1, pf1, o_acc[dt], 0, 0, 0);
        }
        __syncthreads();   // reads of buf[cur] done; buf[cur^1] loads drained
    }

    // ---- epilogue: lane = query l15; d = dt*16 + quad*4 + r
    const float inv = uniformq ? (1.0f / 1024.0f) : (1.0f / l_s);
    const size_t row_g = (size_t)(b*S_ + q0 + wv*16 + l15);
    #pragma unroll
    for (int dt = 0; dt < 5; dt++) {
        union { bf16 hh[4]; uint2 u; } t4;
        #pragma unroll
        for (int r = 0; r < 4; r++) t4.hh[r] = f2b(o_acc[dt][r] * inv);
        *(uint2*)&o[row_g*E_ + h*D_ + dt*16 + quad*4] = t4.u;
    }
}

extern "C" void kernel_launch(void* const* d_in, const int* in_sizes, int n_in,
                              void* d_out, int out_size, void* d_ws, size_t ws_size,
                              hipStream_t stream)
{
    const float* x    = (const float*)d_in[0];
    const int*   cu   = (const int*)  d_in[1];
    const float* cosp = (const float*)d_in[2];
    const float* sinp = (const float*)d_in[3];
    const float* wq   = (const float*)d_in[4];
    const float* bq   = (const float*)d_in[5];
    const float* wk   = (const float*)d_in[6];
    const float* bk   = (const float*)d_in[7];
    const float* wv   = (const float*)d_in[8];
    const float* bv   = (const float*)d_in[9];
    const float* wo   = (const float*)d_in[10];
    const float* bo   = (const float*)d_in[11];
    float* out = (float*)d_out;

    bf16* q   = (bf16*)d_ws;
    bf16* kk  = q   + (size_t)M_ * E_;
    bf16* vt  = kk  + (size_t)M_ * E_;   // transposed V: [B][H][D][S]
    bf16* ao  = vt  + (size_t)M_ * E_;
    bf16* xb  = ao  + (size_t)M_ * E_;
    bf16* wqb = xb  + (size_t)M_ * E_;
    bf16* wkb = wqb + (size_t)E_ * E_;
    bf16* wvb = wkb + (size_t)E_ * E_;
    bf16* wob = wvb + (size_t)E_ * E_;

    // 0) convert x + 4 weight matrices to bf16 (wq/wk rows pair-interleaved)
    cvt_kernel<<<dim3(2560, 5), 256, 0, stream>>>(
        x, wq, wk, wv, wo, xb, wqb, wkb, wvb, wob, M_*E_, E_*E_);

    // 1) QKV projection with FUSED RoPE (q pre-scaled) — rope_kernel removed.
    qkv_gemm_8ph<<<dim3(M_/256, 15), 512, 0, stream>>>(
        xb, wqb, wkb, wvb, bq, bk, bv, cosp, sinp, q, kk, vt);

    // 2) MFMA flash attention v11d (permutation-invariant to the q/k layout)
    attn_mfma<<<512, 512, 0, stream>>>(q, kk, vt, cu, ao);

    // 3) output projection (m97 GEMM, fp32 out, bias fused)
    oproj_gemm<<<dim3(M_/128, E_/128), 256, 0, stream>>>(ao, wob, bo, out);
}